// Round 12
// baseline (677.553 us; speedup 1.0000x reference)
//
#include <hip/hip_runtime.h>
#include <cstdint>
#include <cstddef>

#define BROWS 32768
#define NEXP 8
#define CAP 10240          // per-expert row capacity (E[count]=8192, std~78)
#define CAPBLK (CAP / 64)

typedef short bf16x8 __attribute__((ext_vector_type(8)));
typedef float f32x4 __attribute__((ext_vector_type(4)));

__device__ __forceinline__ unsigned short f2b(float f) {
  union { float f; unsigned u; } v; v.f = f;
  unsigned r = (v.u + 0x7fffu + ((v.u >> 16) & 1u)) >> 16;
  return (unsigned short)r;
}
__device__ __forceinline__ float b2f(unsigned short s) {
  union { unsigned u; float f; } v; v.u = ((unsigned)s) << 16; return v.f;
}
// Fast ELU for the bf16 expert path (round-11 win: 211->175us on v-chain).
__device__ __forceinline__ float fast_elu(float x) {
  return x > 0.f ? x : __expf(x) - 1.f;
}

// ---------------- prep kernels ----------------

__global__ void k_convert_pad(const float* __restrict__ src, unsigned short* __restrict__ dst,
                              int rows, int sc, int dc) {
  int i = blockIdx.x * 256 + threadIdx.x;
  if (i >= rows * dc) return;
  int r = i / dc, c = i % dc;
  float v = (c < sc) ? src[(size_t)r * sc + c] : 0.f;
  dst[i] = f2b(v);
}

// src f32 [E][K][N] -> dst bf16 [E][N][Kpad]
__global__ void k_wtrans(const float* __restrict__ src, unsigned short* __restrict__ dst,
                         int K, int N, int Kpad) {
  __shared__ float tile[32][33];
  int e = blockIdx.z;
  int k0 = blockIdx.x * 32, n0 = blockIdx.y * 32;
  int tx = threadIdx.x, ty = threadIdx.y; // 32 x 8
  for (int i = 0; i < 32; i += 8) {
    int k = k0 + ty + i;
    tile[ty + i][tx] = (k < K) ? src[((size_t)e * K + k) * N + n0 + tx] : 0.f;
  }
  __syncthreads();
  for (int i = 0; i < 32; i += 8) {
    int n = n0 + ty + i;
    dst[((size_t)e * N + n) * Kpad + k0 + tx] = f2b(tile[tx][ty + i]);
  }
}

__global__ void k_zero(int* p, int n) {
  int i = blockIdx.x * 64 + threadIdx.x;
  if (i < n) p[i] = 0;
}

// ---------------- fp32 gate GEMM: Out = ELU(A@W + bias) ----------------
// 128x128 tile, 256 thr, 8x8 micro-tile, named regs.
// Round-12: bounds (256,4) — VGPR=64/LDS=33KB allowed 4 blocks/CU but the
// old (256,2) bound capped TLP at 2 waves/SIMD on a VALU-issue-bound kernel.
template<bool TWOSRC>
__launch_bounds__(256, 4)
__global__ void k_gemm32(const float* __restrict__ A0, int As0,
                         const float* __restrict__ A1, int As1, int Ks,
                         const float* __restrict__ W, const float* __restrict__ bias,
                         int K, int N, float* __restrict__ Out) {
  __shared__ float At[32][132];
  __shared__ float Bs[32][132];

  int tid = threadIdx.x;
  int rb = blockIdx.x * 128, nb = blockIdx.y * 128;
  int tx = tid & 15, tyg = tid >> 4;
  int arow = tid >> 1, aq = (tid & 1) * 16;
  int brow = tid >> 3, bc = (tid & 7) * 16;

  f32x4 c0a = {0,0,0,0}, c0b = {0,0,0,0}, c1a = {0,0,0,0}, c1b = {0,0,0,0};
  f32x4 c2a = {0,0,0,0}, c2b = {0,0,0,0}, c3a = {0,0,0,0}, c3b = {0,0,0,0};
  f32x4 c4a = {0,0,0,0}, c4b = {0,0,0,0}, c5a = {0,0,0,0}, c5b = {0,0,0,0};
  f32x4 c6a = {0,0,0,0}, c6b = {0,0,0,0}, c7a = {0,0,0,0}, c7b = {0,0,0,0};

  float4 a0, a1, a2, a3, b0, b1, b2, b3;
  {
    const float* arp = (!TWOSRC || aq < Ks)
        ? (A0 + (size_t)(rb + arow) * As0 + aq)
        : (A1 + (size_t)(rb + arow) * As1 + (aq - Ks));
    a0 = *(const float4*)(arp);
    a1 = *(const float4*)(arp + 4);
    a2 = *(const float4*)(arp + 8);
    a3 = *(const float4*)(arp + 12);
    const float* brp = W + (size_t)brow * N + nb + bc;
    b0 = *(const float4*)(brp);
    b1 = *(const float4*)(brp + 4);
    b2 = *(const float4*)(brp + 8);
    b3 = *(const float4*)(brp + 12);
  }

  const int NT = K / 32;
  for (int kt = 0; kt < NT; ++kt) {
    __syncthreads();
    At[aq + 0][arow] = a0.x;  At[aq + 1][arow] = a0.y;
    At[aq + 2][arow] = a0.z;  At[aq + 3][arow] = a0.w;
    At[aq + 4][arow] = a1.x;  At[aq + 5][arow] = a1.y;
    At[aq + 6][arow] = a1.z;  At[aq + 7][arow] = a1.w;
    At[aq + 8][arow] = a2.x;  At[aq + 9][arow] = a2.y;
    At[aq + 10][arow] = a2.z; At[aq + 11][arow] = a2.w;
    At[aq + 12][arow] = a3.x; At[aq + 13][arow] = a3.y;
    At[aq + 14][arow] = a3.z; At[aq + 15][arow] = a3.w;
    *(float4*)(&Bs[brow][bc])      = b0;
    *(float4*)(&Bs[brow][bc + 4])  = b1;
    *(float4*)(&Bs[brow][bc + 8])  = b2;
    *(float4*)(&Bs[brow][bc + 12]) = b3;
    __syncthreads();

    if (kt + 1 < NT) {
      int ka = (kt + 1) * 32 + aq;
      const float* arp = (!TWOSRC || ka < Ks)
          ? (A0 + (size_t)(rb + arow) * As0 + ka)
          : (A1 + (size_t)(rb + arow) * As1 + (ka - Ks));
      a0 = *(const float4*)(arp);
      a1 = *(const float4*)(arp + 4);
      a2 = *(const float4*)(arp + 8);
      a3 = *(const float4*)(arp + 12);
      const float* brp = W + (size_t)((kt + 1) * 32 + brow) * N + nb + bc;
      b0 = *(const float4*)(brp);
      b1 = *(const float4*)(brp + 4);
      b2 = *(const float4*)(brp + 8);
      b3 = *(const float4*)(brp + 12);
    }

#pragma unroll 4
    for (int kk = 0; kk < 32; ++kk) {
      float4 av0 = *(const float4*)(&At[kk][tyg * 8]);
      float4 av1 = *(const float4*)(&At[kk][tyg * 8 + 4]);
      f32x4 bva = *(const f32x4*)(&Bs[kk][tx * 8]);
      f32x4 bvb = *(const f32x4*)(&Bs[kk][tx * 8 + 4]);
      c0a += bva * av0.x; c0b += bvb * av0.x;
      c1a += bva * av0.y; c1b += bvb * av0.y;
      c2a += bva * av0.z; c2b += bvb * av0.z;
      c3a += bva * av0.w; c3b += bvb * av0.w;
      c4a += bva * av1.x; c4b += bvb * av1.x;
      c5a += bva * av1.y; c5b += bvb * av1.y;
      c6a += bva * av1.z; c6b += bvb * av1.z;
      c7a += bva * av1.w; c7b += bvb * av1.w;
    }
  }

  float4 bia0 = *(const float4*)(&bias[nb + tx * 8]);
  float4 bia1 = *(const float4*)(&bias[nb + tx * 8 + 4]);

#define GEMM_STORE_ROW(ACA, ACB, I)                                          \
  {                                                                          \
    float o0 = ACA[0] + bia0.x, o1 = ACA[1] + bia0.y;                        \
    float o2 = ACA[2] + bia0.z, o3 = ACA[3] + bia0.w;                        \
    float o4 = ACB[0] + bia1.x, o5 = ACB[1] + bia1.y;                        \
    float o6 = ACB[2] + bia1.z, o7 = ACB[3] + bia1.w;                        \
    o0 = (o0 > 0.f) ? o0 : expm1f(o0); o1 = (o1 > 0.f) ? o1 : expm1f(o1);    \
    o2 = (o2 > 0.f) ? o2 : expm1f(o2); o3 = (o3 > 0.f) ? o3 : expm1f(o3);    \
    o4 = (o4 > 0.f) ? o4 : expm1f(o4); o5 = (o5 > 0.f) ? o5 : expm1f(o5);    \
    o6 = (o6 > 0.f) ? o6 : expm1f(o6); o7 = (o7 > 0.f) ? o7 : expm1f(o7);    \
    float4 w0; w0.x = o0; w0.y = o1; w0.z = o2; w0.w = o3;                   \
    float4 w1; w1.x = o4; w1.y = o5; w1.z = o6; w1.w = o7;                   \
    size_t orow = (size_t)(rb + tyg * 8 + (I)) * N + nb + tx * 8;            \
    *(float4*)(&Out[orow]) = w0;                                             \
    *(float4*)(&Out[orow + 4]) = w1;                                         \
  }
  GEMM_STORE_ROW(c0a, c0b, 0)
  GEMM_STORE_ROW(c1a, c1b, 1)
  GEMM_STORE_ROW(c2a, c2b, 2)
  GEMM_STORE_ROW(c3a, c3b, 3)
  GEMM_STORE_ROW(c4a, c4b, 4)
  GEMM_STORE_ROW(c5a, c5b, 5)
  GEMM_STORE_ROW(c6a, c6b, 6)
  GEMM_STORE_ROW(c7a, c7b, 7)
#undef GEMM_STORE_ROW
}

// ------- gate head: logits, softmax, top-2; per-wave-group counts -------
#define ACTION_SZ (32768 * 12)
#define AUX_OFF   ACTION_SZ
#define IDX_OFF   (ACTION_SZ + 1)
#define SCO_OFF   (ACTION_SZ + 1 + 32768 * 2)

__global__ void k_gatetop(const float* __restrict__ gh2,
                          const float* __restrict__ gw3, const float* __restrict__ gb3,
                          float* __restrict__ out, float* __restrict__ aux,
                          int* __restrict__ bcnt, float* __restrict__ selbuf) {
  int tid = threadIdx.x;
  int b = blockIdx.x * 256 + tid;
  int lane = tid & 63, w = tid >> 6;
  __shared__ float sprob[8];
  if (tid < 8) sprob[tid] = 0.f;
  __syncthreads();

  float lg[8];
#pragma unroll
  for (int j = 0; j < 8; ++j) lg[j] = gb3[j];
  for (int k = 0; k < 128; ++k) {
    float h = gh2[(size_t)b * 128 + k];
#pragma unroll
    for (int j = 0; j < 8; ++j) lg[j] += h * gw3[k * 8 + j];
  }
  float m = lg[0];
#pragma unroll
  for (int j = 1; j < 8; ++j) m = fmaxf(m, lg[j]);
  float probs[8], sum = 0.f;
#pragma unroll
  for (int j = 0; j < 8; ++j) { float p = expf(lg[j] - m); probs[j] = p; sum += p; }
  float inv = 1.f / sum;
#pragma unroll
  for (int j = 0; j < 8; ++j) probs[j] *= inv;
  int i0 = 0, i1;
  float v0 = -1e30f;
#pragma unroll
  for (int j = 0; j < 8; ++j) if (probs[j] > v0) { v0 = probs[j]; i0 = j; }
  float v1 = -1e30f; i1 = (i0 == 0) ? 1 : 0;
#pragma unroll
  for (int j = 0; j < 8; ++j) if (j != i0 && probs[j] > v1) { v1 = probs[j]; i1 = j; }
  float wsum = v0 + v1 + 1e-9f;
  float w0 = v0 / wsum, w1 = v1 / wsum;

  out[IDX_OFF + (size_t)b * 2 + 0] = (float)i0;
  out[IDX_OFF + (size_t)b * 2 + 1] = (float)i1;
  out[SCO_OFF + (size_t)b * 2 + 0] = v0;
  out[SCO_OFF + (size_t)b * 2 + 1] = v1;
  selbuf[(size_t)b * 4 + 0] = (float)i0;
  selbuf[(size_t)b * 4 + 1] = (float)i1;
  selbuf[(size_t)b * 4 + 2] = w0;
  selbuf[(size_t)b * 4 + 3] = w1;

#pragma unroll
  for (int e2 = 0; e2 < 8; ++e2) {
    unsigned long long mm = __ballot(i0 == e2) | __ballot(i1 == e2);
    if (lane == 0) bcnt[(blockIdx.x * 4 + w) * 8 + e2] = __popcll(mm);
  }

#pragma unroll
  for (int j = 0; j < 8; ++j) {
    float p = probs[j];
#pragma unroll
    for (int mk = 1; mk <= 32; mk <<= 1) p += __shfl_xor(p, mk, 64);
    if (lane == 0) atomicAdd(&sprob[j], p);
  }
  __syncthreads();
  if (tid < 8) atomicAdd(&aux[tid], sprob[tid]);
}

// two-level exclusive scan of bcnt (512 groups x 8 experts) -> bbase, cnt
__global__ void k_scan(const int* __restrict__ bcnt, int* __restrict__ bbase,
                       int* __restrict__ cnt) {
  __shared__ int psum[8][8]; // [seg][e2]
  int tid = threadIdx.x;
  int e2 = tid & 7, seg = tid >> 3;
  int s = 0;
  for (int i = 0; i < 64; ++i) s += bcnt[(seg * 64 + i) * 8 + e2];
  psum[seg][e2] = s;
  __syncthreads();
  int base = 0;
  for (int t = 0; t < seg; ++t) base += psum[t][e2];
  int run = base;
  for (int i = 0; i < 64; ++i) {
    bbase[(seg * 64 + i) * 8 + e2] = run;
    run += bcnt[(seg * 64 + i) * 8 + e2];
  }
  if (seg == 7) cnt[e2] = run;
}

// fill perm sorted by row within each expert (deterministic, ballot ranks)
__global__ void k_fill(const float* __restrict__ selbuf, const int* __restrict__ bbase,
                       int* __restrict__ perm) {
  int gidx = blockIdx.x;          // 512 groups
  int lane = threadIdx.x;         // 64
  int b = gidx * 64 + lane;
  int i0 = (int)selbuf[(size_t)b * 4 + 0];
  int i1 = (int)selbuf[(size_t)b * 4 + 1];
  unsigned long long lt = (1ull << lane) - 1ull;
#pragma unroll
  for (int e2 = 0; e2 < 8; ++e2) {
    unsigned long long mm = __ballot(i0 == e2) | __ballot(i1 == e2);
    if (i0 == e2 || i1 == e2) {
      int s = bbase[gidx * 8 + e2] + (int)__popcll(mm & lt);
      if (s < CAP) perm[e2 * CAP + s] = b;
    }
  }
}

__global__ void k_auxfinal(const int* __restrict__ cnt, const float* __restrict__ aux,
                           float* __restrict__ out) {
  if (threadIdx.x == 0) {
    float s = 0.f;
#pragma unroll
    for (int e = 0; e < 8; ++e) {
      float f = (float)cnt[e] / (32768.f * 2.f);
      float P = aux[e] / 32768.f;
      s += f * P;
    }
    out[AUX_OFF] = 8.f * s;
  }
}

// ------- fused expert chain: 2 layers (GEMM+ELU+LN each) in one kernel -------
// Round-12: 2-deep B prefetch queue (q0/q1/qt rotation, compile-time indices)
// to cover ~200-300cy L2 latency with ~160cy of MFMA (was 1-deep = ~80cy).
// s-chain (PAN<=256) gets (512,8) bounds -> 4 blocks/CU.
template<int K1, int N1, int N2, bool GATHER, bool FCHAIN>
__launch_bounds__(512, ((K1 > 256 || N1 > 256) ? 4 : 8))
__global__ void k_chain(const unsigned short* __restrict__ A, int As,
                        const int* __restrict__ perm, const int* __restrict__ cnt,
                        const unsigned short* __restrict__ W1, const float* __restrict__ b1v,
                        const float* __restrict__ g1v, const float* __restrict__ h1v,
                        const unsigned short* __restrict__ W2, const float* __restrict__ b2v,
                        const float* __restrict__ g2v, const float* __restrict__ h2v,
                        unsigned short* __restrict__ Out, int Os, int Ocol,
                        const float* __restrict__ fw3, const float* __restrict__ fb3,
                        float* __restrict__ allout) {
  constexpr int WC1 = N1 / 8, NF1 = WC1 / 16;
  constexpr int WC2 = N2 / 8, NF2 = WC2 / 16;
  constexpr int NK1 = K1 / 64, NK2 = N1 / 64;
  constexpr int NS1 = NK1 * 2, NS2 = NK2 * 2;
  constexpr int PAN = (K1 > N1) ? K1 : N1;
  constexpr int NCH = N2 / 128;
  static_assert(NF1 >= 1 && NF2 >= 1 && K1 % 64 == 0 && N1 % 128 == 0, "shape");

  __shared__ unsigned short smP[64 * PAN];   // A1 panel -> h1 panel -> staging
  __shared__ float red[64][8][2];
  __shared__ float rowstat[64][2];

  int e = blockIdx.y;
  int count = cnt[e]; if (count > CAP) count = CAP;
  int rb = blockIdx.x * 64;
  if (rb >= count) return;

  int tid = threadIdx.x;
  int lane = tid & 63, wn = tid >> 6;
  int l15 = lane & 15, g = lane >> 4;

  // ---- stage A1 panel (64 x K1), single barrier ----
  {
    int srow = tid >> 3, schunk = tid & 7;
    int slot = rb + srow;
    size_t arow;
    if (GATHER) {
      int s = slot < count ? slot : count - 1;
      arow = (size_t)perm[e * CAP + s];
    } else {
      arow = (size_t)e * CAP + slot;
    }
    const unsigned short* aptr = A + arow * As + schunk * 8;
    int lws = srow * K1 + ((schunk ^ (srow & 7)) << 3);
    uint4 stg[NK1];
#pragma unroll
    for (int kt = 0; kt < NK1; ++kt) stg[kt] = *(const uint4*)(aptr + kt * 64);
#pragma unroll
    for (int kt = 0; kt < NK1; ++kt) *(uint4*)(&smP[lws + kt * 64]) = stg[kt];
  }

  // ---- GEMM1: acc1 = A1 @ W1 (2-deep B prefetch) ----
  const unsigned short* W1e = W1 + (size_t)e * N1 * K1;
  const unsigned short* bp1[NF1];
#pragma unroll
  for (int nf = 0; nf < NF1; ++nf)
    bp1[nf] = W1e + (size_t)(wn * WC1 + nf * 16 + l15) * K1 + g * 8;

  f32x4 acc1[4][NF1] = {};
  bf16x8 q0[NF1], q1[NF1], qt[NF1];
#pragma unroll
  for (int nf = 0; nf < NF1; ++nf) q0[nf] = *(const bf16x8*)(bp1[nf]);
  if (NS1 > 1) {
#pragma unroll
    for (int nf = 0; nf < NF1; ++nf) q1[nf] = *(const bf16x8*)(bp1[nf] + 32);
  }

  __syncthreads();

#pragma unroll
  for (int ks = 0; ks < NS1; ++ks) {
    const int kt = ks >> 1, kk = ks & 1;
    if (ks + 2 < NS1) {
      const int noff = (ks + 2) * 32;
#pragma unroll
      for (int nf = 0; nf < NF1; ++nf) qt[nf] = *(const bf16x8*)(bp1[nf] + noff);
    }
#pragma unroll
    for (int mf = 0; mf < 4; ++mf) {
      int row = mf * 16 + l15;
      int chunk = (kk * 4 + g) ^ (row & 7);
      bf16x8 a = *(const bf16x8*)(&smP[row * K1 + kt * 64 + chunk * 8]);
#pragma unroll
      for (int nf = 0; nf < NF1; ++nf)
        acc1[mf][nf] = __builtin_amdgcn_mfma_f32_16x16x32_bf16(a, q0[nf], acc1[mf][nf], 0, 0, 0);
    }
#pragma unroll
    for (int nf = 0; nf < NF1; ++nf) q0[nf] = q1[nf];
    if (ks + 2 < NS1) {
#pragma unroll
      for (int nf = 0; nf < NF1; ++nf) q1[nf] = qt[nf];
    }
  }

  // ---- bias + ELU + LN over N1 ----
  {
    float bia[NF1], gam[NF1], bet[NF1];
#pragma unroll
    for (int nf = 0; nf < NF1; ++nf) {
      int n = wn * WC1 + nf * 16 + l15;
      bia[nf] = b1v[e * N1 + n]; gam[nf] = g1v[e * N1 + n]; bet[nf] = h1v[e * N1 + n];
    }
#pragma unroll
    for (int mf = 0; mf < 4; ++mf)
#pragma unroll
      for (int nf = 0; nf < NF1; ++nf)
#pragma unroll
        for (int r = 0; r < 4; ++r)
          acc1[mf][nf][r] = fast_elu(acc1[mf][nf][r] + bia[nf]);
#pragma unroll
    for (int mf = 0; mf < 4; ++mf)
#pragma unroll
      for (int r = 0; r < 4; ++r) {
        float s1 = 0.f, s2 = 0.f;
#pragma unroll
        for (int nf = 0; nf < NF1; ++nf) {
          float x = acc1[mf][nf][r];
          s1 += x; s2 += x * x;
        }
#pragma unroll
        for (int mk = 1; mk <= 8; mk <<= 1) {
          s1 += __shfl_xor(s1, mk, 64);
          s2 += __shfl_xor(s2, mk, 64);
        }
        if (l15 == 0) {
          int row = mf * 16 + g * 4 + r;
          red[row][wn][0] = s1;
          red[row][wn][1] = s2;
        }
      }
    __syncthreads();   // all waves done reading A1 panel
    if (tid < 64) {
      float s1 = 0.f, s2 = 0.f;
#pragma unroll
      for (int j = 0; j < 8; ++j) { s1 += red[tid][j][0]; s2 += red[tid][j][1]; }
      float mean = s1 / (float)N1;
      float var = s2 / (float)N1 - mean * mean;
      rowstat[tid][0] = mean;
      rowstat[tid][1] = rsqrtf(var + 1e-5f);
    }
    __syncthreads();
    // normalize + write h1 into panel (stride N1, same XOR swizzle)
#pragma unroll
    for (int mf = 0; mf < 4; ++mf)
#pragma unroll
      for (int r = 0; r < 4; ++r) {
        int row = mf * 16 + g * 4 + r;
        float mean = rowstat[row][0], rstd = rowstat[row][1];
#pragma unroll
        for (int nf = 0; nf < NF1; ++nf) {
          int col = wn * WC1 + nf * 16 + l15;
          float y = (acc1[mf][nf][r] - mean) * rstd * gam[nf] + bet[nf];
          int pos = (col & ~63) + ((((col >> 3) & 7) ^ (row & 7)) << 3) + (col & 7);
          smP[row * N1 + pos] = f2b(y);
        }
      }
  }

  // ---- GEMM2: acc2 = h1 @ W2 (2-deep B prefetch) ----
  const unsigned short* W2e = W2 + (size_t)e * N2 * N1;
  const unsigned short* bp2[NF2];
#pragma unroll
  for (int nf = 0; nf < NF2; ++nf)
    bp2[nf] = W2e + (size_t)(wn * WC2 + nf * 16 + l15) * N1 + g * 8;

  f32x4 acc2[4][NF2] = {};
  bf16x8 p0[NF2], p1[NF2], pt[NF2];
#pragma unroll
  for (int nf = 0; nf < NF2; ++nf) p0[nf] = *(const bf16x8*)(bp2[nf]);
  if (NS2 > 1) {
#pragma unroll
    for (int nf = 0; nf < NF2; ++nf) p1[nf] = *(const bf16x8*)(bp2[nf] + 32);
  }

  __syncthreads();   // h1 panel complete

#pragma unroll
  for (int ks = 0; ks < NS2; ++ks) {
    const int kt = ks >> 1, kk = ks & 1;
    if (ks + 2 < NS2) {
      const int noff = (ks + 2) * 32;
#pragma unroll
      for (int nf = 0; nf < NF2; ++nf) pt[nf] = *(const bf16x8*)(bp2[nf] + noff);
    }
#pragma unroll
    for (int mf = 0; mf < 4; ++mf) {
      int row = mf * 16 + l15;
      int chunk = (kk * 4 + g) ^ (row & 7);
      bf16x8 a = *(const bf16x8*)(&smP[row * N1 + kt * 64 + chunk * 8]);
#pragma unroll
      for (int nf = 0; nf < NF2; ++nf)
        acc2[mf][nf] = __builtin_amdgcn_mfma_f32_16x16x32_bf16(a, p0[nf], acc2[mf][nf], 0, 0, 0);
    }
#pragma unroll
    for (int nf = 0; nf < NF2; ++nf) p0[nf] = p1[nf];
    if (ks + 2 < NS2) {
#pragma unroll
      for (int nf = 0; nf < NF2; ++nf) p1[nf] = pt[nf];
    }
  }

  // ---- bias + ELU + LN over N2 ----
  {
    float bia[NF2], gam[NF2], bet[NF2];
#pragma unroll
    for (int nf = 0; nf < NF2; ++nf) {
      int n = wn * WC2 + nf * 16 + l15;
      bia[nf] = b2v[e * N2 + n]; gam[nf] = g2v[e * N2 + n]; bet[nf] = h2v[e * N2 + n];
    }
#pragma unroll
    for (int mf = 0; mf < 4; ++mf)
#pragma unroll
      for (int nf = 0; nf < NF2; ++nf)
#pragma unroll
        for (int r = 0; r < 4; ++r)
          acc2[mf][nf][r] = fast_elu(acc2[mf][nf][r] + bia[nf]);
#pragma unroll
    for (int mf = 0; mf < 4; ++mf)
#pragma unroll
      for (int r = 0; r < 4; ++r) {
        float s1 = 0.f, s2 = 0.f;
#pragma unroll
        for (int nf = 0; nf < NF2; ++nf) {
          float x = acc2[mf][nf][r];
          s1 += x; s2 += x * x;
        }
#pragma unroll
        for (int mk = 1; mk <= 8; mk <<= 1) {
          s1 += __shfl_xor(s1, mk, 64);
          s2 += __shfl_xor(s2, mk, 64);
        }
        if (l15 == 0) {
          int row = mf * 16 + g * 4 + r;
          red[row][wn][0] = s1;
          red[row][wn][1] = s2;
        }
      }
    __syncthreads();   // all waves done reading h1 panel
    if (tid < 64) {
      float s1 = 0.f, s2 = 0.f;
#pragma unroll
      for (int j = 0; j < 8; ++j) { s1 += red[tid][j][0]; s2 += red[tid][j][1]; }
      float mean = s1 / (float)N2;
      float var = s2 / (float)N2 - mean * mean;
      rowstat[tid][0] = mean;
      rowstat[tid][1] = rsqrtf(var + 1e-5f);
    }
    __syncthreads();
#pragma unroll
    for (int mf = 0; mf < 4; ++mf)
#pragma unroll
      for (int r = 0; r < 4; ++r) {
        int row = mf * 16 + g * 4 + r;
        float mean = rowstat[row][0], rstd = rowstat[row][1];
#pragma unroll
        for (int nf = 0; nf < NF2; ++nf)
          acc2[mf][nf][r] = (acc2[mf][nf][r] - mean) * rstd * gam[nf] + bet[nf];
      }
  }

  if constexpr (!FCHAIN) {
    // ---- vectorized store via LDS staging, 128-col chunks ----
    unsigned short* sm16 = &smP[0];       // [64][128]
    int wq = (wn * WC2) >> 7;
    for (int q = 0; q < NCH; ++q) {
      __syncthreads();
      if (NCH == 1 || wq == q) {
#pragma unroll
        for (int mf = 0; mf < 4; ++mf)
#pragma unroll
          for (int r = 0; r < 4; ++r) {
            int row = mf * 16 + g * 4 + r;
            int s = row & 7;
#pragma unroll
            for (int nf = 0; nf < NF2; ++nf) {
              int lc = (wn * WC2 + nf * 16 + l15) - q * 128;   // 0..127
              if (NCH == 1 || (lc >= 0 && lc < 128)) {
                int pos = (((lc >> 3) ^ s) << 3) | (lc & 7);
                sm16[row * 128 + pos] = f2b(acc2[mf][nf][r]);
              }
            }
          }
      }
      __syncthreads();
#pragma unroll
      for (int i = 0; i < 2; ++i) {
        int t = tid + i * 512;
        int row = t >> 4, cc = t & 15;
        int oc = cc ^ (row & 7);
        uint4 v = *(const uint4*)(&sm16[row * 128 + cc * 8]);
        *(uint4*)(&Out[((size_t)e * CAP + rb + row) * Os + Ocol + q * 128 + oc * 8]) = v;
      }
    }
  } else {
    // ---- f-chain: h2 to LDS (padded) + fw3 staged to LDS, 256->12 head ----
    __syncthreads();   // acc2 final everywhere; panel free
    constexpr int H2S = 264;  // row stride (pad 8 to break bank alignment)
    float* wsh = (float*)(&smP[64 * H2S]);   // 12 KB, disjoint from h2 rows
#pragma unroll
    for (int mf = 0; mf < 4; ++mf)
#pragma unroll
      for (int r = 0; r < 4; ++r) {
        int row = mf * 16 + g * 4 + r;
#pragma unroll
        for (int nf = 0; nf < NF2; ++nf) {
          int col = wn * WC2 + nf * 16 + l15;
          smP[row * H2S + col] = f2b(acc2[mf][nf][r]);
        }
      }
    for (int i = tid; i < 256 * 12; i += 512) wsh[i] = fw3[(size_t)e * 256 * 12 + i];
    __syncthreads();
#pragma unroll
    for (int it = 0; it < 2; ++it) {
      int idx = tid + it * 512;
      if (idx < 768) {
        int row = idx / 12, j = idx - row * 12;
        int slot2 = rb + row;
        if (slot2 < count) {
          float a = fb3[e * 12 + j];
          for (int c = 0; c < 256; ++c)
            a += b2f(smP[row * H2S + c]) * wsh[c * 12 + j];
          int arow = perm[e * CAP + slot2];
          allout[((size_t)arow * 8 + e) * 12 + j] = a;
        }
      }
    }
  }
}

// ------- mix: weighted sum of the two selected expert outputs -------
__global__ void k_mix(const float* __restrict__ selbuf, const float* __restrict__ allout,
                      float* __restrict__ out) {
  int b = blockIdx.x * 256 + threadIdx.x;
  int i0 = (int)selbuf[(size_t)b * 4 + 0];
  int i1 = (int)selbuf[(size_t)b * 4 + 1];
  float w0 = selbuf[(size_t)b * 4 + 2];
  float w1 = selbuf[(size_t)b * 4 + 3];
  const float* a0 = allout + ((size_t)b * 8 + i0) * 12;
  const float* a1 = allout + ((size_t)b * 8 + i1) * 12;
#pragma unroll
  for (int j = 0; j < 12; ++j)
    out[(size_t)b * 12 + j] = w0 * a0[j] + w1 * a1[j];
}

// ---------------- host ----------------

extern "C" void kernel_launch(void* const* d_in, const int* in_sizes, int n_in,
                              void* d_out, int out_size, void* d_ws, size_t ws_size,
                              hipStream_t stream) {
  const float* state = (const float*)d_in[0];
  const float* vlm   = (const float*)d_in[1];
  const float* sw1 = (const float*)d_in[2];  const float* sb1 = (const float*)d_in[3];
  const float* sg1 = (const float*)d_in[4];  const float* sh1 = (const float*)d_in[5];
  const float* sw2 = (const float*)d_in[6];  const float* sb2 = (const float*)d_in[7];
  const float* sg2 = (const float*)d_in[8];  const float* sh2 = (const float*)d_in[9];
  const float* vw1 = (const float*)d_in[10]; const float* vb1 = (const float*)d_in[11];
  const float* vg1 = (const float*)d_in[12]; const float* vh1 = (const float*)d_in[13];
  const float* vw2 = (const float*)d_in[14]; const float* vb2 = (const float*)d_in[15];
  const float* vg2 = (const float*)d_in[16]; const float* vh2 = (const float*)d_in[17];
  const float* fw1 = (const float*)d_in[18]; const float* fb1 = (const float*)d_in[19];
  const float* fg1 = (const float*)d_in[20]; const float* fh1 = (const float*)d_in[21];
  const float* fw2 = (const float*)d_in[22]; const float* fb2 = (const float*)d_in[23];
  const float* fg2 = (const float*)d_in[24]; const float* fh2 = (const float*)d_in[25];
  const float* fw3 = (const float*)d_in[26]; const float* fb3 = (const float*)d_in[27];
  const float* gw1 = (const float*)d_in[28]; const float* gb1 = (const float*)d_in[29];
  const float* gw2 = (const float*)d_in[30]; const float* gb2 = (const float*)d_in[31];
  const float* gw3 = (const float*)d_in[32]; const float* gb3 = (const float*)d_in[33];

  // ---- workspace (~182 MB) ----
  char* ws = (char*)d_ws;
  size_t off = 0;
  auto alloc = [&](size_t bytes) -> char* {
    char* p = ws + off;
    off = (off + bytes + 255) & ~(size_t)255;
    return p;
  };
  unsigned short* st_bf = (unsigned short*)alloc((size_t)BROWS * 128 * 2);      // 8.4 MB
  unsigned short* vl_bf = (unsigned short*)alloc((size_t)BROWS * 512 * 2);      // 33.6 MB
  unsigned short* bufF  = (unsigned short*)alloc((size_t)NEXP * CAP * 384 * 2); // 62.9 MB
  float* allout = (float*)alloc((size_t)BROWS * 8 * 12 * 4);                    // 12.6 MB
  float* gh1    = (float*)alloc((size_t)BROWS * 256 * 4);                       // 33.6 MB
  float* gh2    = (float*)alloc((size_t)BROWS * 128 * 4);                       // 16.8 MB
  float* selbuf = (float*)alloc((size_t)BROWS * 4 * 4);
  int*   perm   = (int*)alloc((size_t)NEXP * CAP * 4);
  int*   bcnt   = (int*)alloc(512 * 8 * 4);
  int*   bbase  = (int*)alloc(512 * 8 * 4);
  char*  cntaux = alloc(256);  // cnt: 8 ints at +0, aux: 8 floats at +64
  int*   cnt = (int*)cntaux;
  float* aux = (float*)(cntaux + 64);
  unsigned short* wt_s1 = (unsigned short*)alloc((size_t)8 * 256 * 128 * 2);
  unsigned short* wt_s2 = (unsigned short*)alloc((size_t)8 * 128 * 256 * 2);
  unsigned short* wt_v1 = (unsigned short*)alloc((size_t)8 * 512 * 512 * 2);
  unsigned short* wt_v2 = (unsigned short*)alloc((size_t)8 * 256 * 512 * 2);
  unsigned short* wt_f1 = (unsigned short*)alloc((size_t)8 * 512 * 384 * 2);
  unsigned short* wt_f2 = (unsigned short*)alloc((size_t)8 * 256 * 512 * 2);
  (void)ws_size; (void)in_sizes; (void)n_in; (void)out_size;

  float* outf = (float*)d_out;

  // prep
  k_convert_pad<<<(BROWS * 128 + 255) / 256, 256, 0, stream>>>(state, st_bf, BROWS, 96, 128);
  k_convert_pad<<<(BROWS * 512 + 255) / 256, 256, 0, stream>>>(vlm, vl_bf, BROWS, 512, 512);
  k_wtrans<<<dim3(4, 8, 8),   dim3(32, 8), 0, stream>>>(sw1, wt_s1, 96, 256, 128);
  k_wtrans<<<dim3(8, 4, 8),   dim3(32, 8), 0, stream>>>(sw2, wt_s2, 256, 128, 256);
  k_wtrans<<<dim3(16, 16, 8), dim3(32, 8), 0, stream>>>(vw1, wt_v1, 512, 512, 512);
  k_wtrans<<<dim3(16, 8, 8),  dim3(32, 8), 0, stream>>>(vw2, wt_v2, 512, 256, 512);
  k_wtrans<<<dim3(12, 16, 8), dim3(32, 8), 0, stream>>>(fw1, wt_f1, 384, 512, 384);
  k_wtrans<<<dim3(16, 8, 8),  dim3(32, 8), 0, stream>>>(fw2, wt_f2, 512, 256, 512);
  k_zero<<<1, 64, 0, stream>>>((int*)cntaux, 64);

  // gate (fp32 for exact top-k)
  k_gemm32<true><<<dim3(256, 2), 256, 0, stream>>>(state, 96, vlm, 512, 96,
                                                   gw1, gb1, 608, 256, gh1);
  k_gemm32<false><<<dim3(256, 1), 256, 0, stream>>>(gh1, 256, nullptr, 0, 0,
                                                    gw2, gb2, 256, 128, gh2);
  k_gatetop<<<BROWS / 256, 256, 0, stream>>>(gh2, gw3, gb3, outf, aux, bcnt, selbuf);
  k_scan<<<1, 64, 0, stream>>>(bcnt, bbase, cnt);
  k_fill<<<512, 64, 0, stream>>>(selbuf, bbase, perm);
  k_auxfinal<<<1, 64, 0, stream>>>(cnt, aux, outf);

  // fused expert chains
  dim3 lg(CAPBLK, NEXP);
  // s-chain: st_bf -> 256 -> 128 -> bufF[:, 0:128]
  k_chain<128, 256, 128, true, false><<<lg, 512, 0, stream>>>(
      st_bf, 128, perm, cnt,
      wt_s1, sb1, sg1, sh1, wt_s2, sb2, sg2, sh2,
      bufF, 384, 0, nullptr, nullptr, nullptr);
  // v-chain: vl_bf -> 512 -> 256 -> bufF[:, 128:384]
  k_chain<512, 512, 256, true, false><<<lg, 512, 0, stream>>>(
      vl_bf, 512, perm, cnt,
      wt_v1, vb1, vg1, vh1, wt_v2, vb2, vg2, vh2,
      bufF, 384, 128, nullptr, nullptr, nullptr);
  // f-chain: bufF -> 512 -> 256 -> head 12 -> allout
  k_chain<384, 512, 256, false, true><<<lg, 512, 0, stream>>>(
      bufF, 384, perm, cnt,
      wt_f1, fb1, fg1, fh1, wt_f2, fb2, fg2, fh2,
      nullptr, 0, 0, fw3, fb3, allout);

  k_mix<<<BROWS / 256, 256, 0, stream>>>(selbuf, allout, outf);
}

// Round 13
// 628.547 us; speedup vs baseline: 1.0780x; 1.0780x over previous
//
#include <hip/hip_runtime.h>
#include <cstdint>
#include <cstddef>

#define BROWS 32768
#define NEXP 8
#define CAP 10240          // per-expert row capacity (E[count]=8192, std~78)
#define CAPBLK (CAP / 64)

typedef short bf16x8 __attribute__((ext_vector_type(8)));
typedef float f32x4 __attribute__((ext_vector_type(4)));

__device__ __forceinline__ unsigned short f2b(float f) {
  union { float f; unsigned u; } v; v.f = f;
  unsigned r = (v.u + 0x7fffu + ((v.u >> 16) & 1u)) >> 16;
  return (unsigned short)r;
}
__device__ __forceinline__ float b2f(unsigned short s) {
  union { unsigned u; float f; } v; v.u = ((unsigned)s) << 16; return v.f;
}
// Fast ELU for the bf16 expert path (round-11 win: 211->175us on v-chain).
__device__ __forceinline__ float fast_elu(float x) {
  return x > 0.f ? x : __expf(x) - 1.f;
}

// ---------------- prep kernels ----------------

__global__ void k_convert_pad(const float* __restrict__ src, unsigned short* __restrict__ dst,
                              int rows, int sc, int dc) {
  int i = blockIdx.x * 256 + threadIdx.x;
  if (i >= rows * dc) return;
  int r = i / dc, c = i % dc;
  float v = (c < sc) ? src[(size_t)r * sc + c] : 0.f;
  dst[i] = f2b(v);
}

// src f32 [E][K][N] -> dst bf16 [E][N][Kpad]
__global__ void k_wtrans(const float* __restrict__ src, unsigned short* __restrict__ dst,
                         int K, int N, int Kpad) {
  __shared__ float tile[32][33];
  int e = blockIdx.z;
  int k0 = blockIdx.x * 32, n0 = blockIdx.y * 32;
  int tx = threadIdx.x, ty = threadIdx.y; // 32 x 8
  for (int i = 0; i < 32; i += 8) {
    int k = k0 + ty + i;
    tile[ty + i][tx] = (k < K) ? src[((size_t)e * K + k) * N + n0 + tx] : 0.f;
  }
  __syncthreads();
  for (int i = 0; i < 32; i += 8) {
    int n = n0 + ty + i;
    dst[((size_t)e * N + n) * Kpad + k0 + tx] = f2b(tile[tx][ty + i]);
  }
}

__global__ void k_zero(int* p, int n) {
  int i = blockIdx.x * 64 + threadIdx.x;
  if (i < n) p[i] = 0;
}

// ---------------- fp32 gate GEMM: Out = ELU(A@W + bias) ----------------
// 128x128 tile, 256 thr, 8x8 micro-tile, named regs, bounds (256,4).
template<bool TWOSRC>
__launch_bounds__(256, 4)
__global__ void k_gemm32(const float* __restrict__ A0, int As0,
                         const float* __restrict__ A1, int As1, int Ks,
                         const float* __restrict__ W, const float* __restrict__ bias,
                         int K, int N, float* __restrict__ Out) {
  __shared__ float At[32][132];
  __shared__ float Bs[32][132];

  int tid = threadIdx.x;
  int rb = blockIdx.x * 128, nb = blockIdx.y * 128;
  int tx = tid & 15, tyg = tid >> 4;
  int arow = tid >> 1, aq = (tid & 1) * 16;
  int brow = tid >> 3, bc = (tid & 7) * 16;

  f32x4 c0a = {0,0,0,0}, c0b = {0,0,0,0}, c1a = {0,0,0,0}, c1b = {0,0,0,0};
  f32x4 c2a = {0,0,0,0}, c2b = {0,0,0,0}, c3a = {0,0,0,0}, c3b = {0,0,0,0};
  f32x4 c4a = {0,0,0,0}, c4b = {0,0,0,0}, c5a = {0,0,0,0}, c5b = {0,0,0,0};
  f32x4 c6a = {0,0,0,0}, c6b = {0,0,0,0}, c7a = {0,0,0,0}, c7b = {0,0,0,0};

  float4 a0, a1, a2, a3, b0, b1, b2, b3;
  {
    const float* arp = (!TWOSRC || aq < Ks)
        ? (A0 + (size_t)(rb + arow) * As0 + aq)
        : (A1 + (size_t)(rb + arow) * As1 + (aq - Ks));
    a0 = *(const float4*)(arp);
    a1 = *(const float4*)(arp + 4);
    a2 = *(const float4*)(arp + 8);
    a3 = *(const float4*)(arp + 12);
    const float* brp = W + (size_t)brow * N + nb + bc;
    b0 = *(const float4*)(brp);
    b1 = *(const float4*)(brp + 4);
    b2 = *(const float4*)(brp + 8);
    b3 = *(const float4*)(brp + 12);
  }

  const int NT = K / 32;
  for (int kt = 0; kt < NT; ++kt) {
    __syncthreads();
    At[aq + 0][arow] = a0.x;  At[aq + 1][arow] = a0.y;
    At[aq + 2][arow] = a0.z;  At[aq + 3][arow] = a0.w;
    At[aq + 4][arow] = a1.x;  At[aq + 5][arow] = a1.y;
    At[aq + 6][arow] = a1.z;  At[aq + 7][arow] = a1.w;
    At[aq + 8][arow] = a2.x;  At[aq + 9][arow] = a2.y;
    At[aq + 10][arow] = a2.z; At[aq + 11][arow] = a2.w;
    At[aq + 12][arow] = a3.x; At[aq + 13][arow] = a3.y;
    At[aq + 14][arow] = a3.z; At[aq + 15][arow] = a3.w;
    *(float4*)(&Bs[brow][bc])      = b0;
    *(float4*)(&Bs[brow][bc + 4])  = b1;
    *(float4*)(&Bs[brow][bc + 8])  = b2;
    *(float4*)(&Bs[brow][bc + 12]) = b3;
    __syncthreads();

    if (kt + 1 < NT) {
      int ka = (kt + 1) * 32 + aq;
      const float* arp = (!TWOSRC || ka < Ks)
          ? (A0 + (size_t)(rb + arow) * As0 + ka)
          : (A1 + (size_t)(rb + arow) * As1 + (ka - Ks));
      a0 = *(const float4*)(arp);
      a1 = *(const float4*)(arp + 4);
      a2 = *(const float4*)(arp + 8);
      a3 = *(const float4*)(arp + 12);
      const float* brp = W + (size_t)((kt + 1) * 32 + brow) * N + nb + bc;
      b0 = *(const float4*)(brp);
      b1 = *(const float4*)(brp + 4);
      b2 = *(const float4*)(brp + 8);
      b3 = *(const float4*)(brp + 12);
    }

#pragma unroll 4
    for (int kk = 0; kk < 32; ++kk) {
      float4 av0 = *(const float4*)(&At[kk][tyg * 8]);
      float4 av1 = *(const float4*)(&At[kk][tyg * 8 + 4]);
      f32x4 bva = *(const f32x4*)(&Bs[kk][tx * 8]);
      f32x4 bvb = *(const f32x4*)(&Bs[kk][tx * 8 + 4]);
      c0a += bva * av0.x; c0b += bvb * av0.x;
      c1a += bva * av0.y; c1b += bvb * av0.y;
      c2a += bva * av0.z; c2b += bvb * av0.z;
      c3a += bva * av0.w; c3b += bvb * av0.w;
      c4a += bva * av1.x; c4b += bvb * av1.x;
      c5a += bva * av1.y; c5b += bvb * av1.y;
      c6a += bva * av1.z; c6b += bvb * av1.z;
      c7a += bva * av1.w; c7b += bvb * av1.w;
    }
  }

  float4 bia0 = *(const float4*)(&bias[nb + tx * 8]);
  float4 bia1 = *(const float4*)(&bias[nb + tx * 8 + 4]);

#define GEMM_STORE_ROW(ACA, ACB, I)                                          \
  {                                                                          \
    float o0 = ACA[0] + bia0.x, o1 = ACA[1] + bia0.y;                        \
    float o2 = ACA[2] + bia0.z, o3 = ACA[3] + bia0.w;                        \
    float o4 = ACB[0] + bia1.x, o5 = ACB[1] + bia1.y;                        \
    float o6 = ACB[2] + bia1.z, o7 = ACB[3] + bia1.w;                        \
    o0 = (o0 > 0.f) ? o0 : expm1f(o0); o1 = (o1 > 0.f) ? o1 : expm1f(o1);    \
    o2 = (o2 > 0.f) ? o2 : expm1f(o2); o3 = (o3 > 0.f) ? o3 : expm1f(o3);    \
    o4 = (o4 > 0.f) ? o4 : expm1f(o4); o5 = (o5 > 0.f) ? o5 : expm1f(o5);    \
    o6 = (o6 > 0.f) ? o6 : expm1f(o6); o7 = (o7 > 0.f) ? o7 : expm1f(o7);    \
    float4 w0; w0.x = o0; w0.y = o1; w0.z = o2; w0.w = o3;                   \
    float4 w1; w1.x = o4; w1.y = o5; w1.z = o6; w1.w = o7;                   \
    size_t orow = (size_t)(rb + tyg * 8 + (I)) * N + nb + tx * 8;            \
    *(float4*)(&Out[orow]) = w0;                                             \
    *(float4*)(&Out[orow + 4]) = w1;                                         \
  }
  GEMM_STORE_ROW(c0a, c0b, 0)
  GEMM_STORE_ROW(c1a, c1b, 1)
  GEMM_STORE_ROW(c2a, c2b, 2)
  GEMM_STORE_ROW(c3a, c3b, 3)
  GEMM_STORE_ROW(c4a, c4b, 4)
  GEMM_STORE_ROW(c5a, c5b, 5)
  GEMM_STORE_ROW(c6a, c6b, 6)
  GEMM_STORE_ROW(c7a, c7b, 7)
#undef GEMM_STORE_ROW
}

// ------- gate head: logits, softmax, top-2; per-wave-group counts -------
#define ACTION_SZ (32768 * 12)
#define AUX_OFF   ACTION_SZ
#define IDX_OFF   (ACTION_SZ + 1)
#define SCO_OFF   (ACTION_SZ + 1 + 32768 * 2)

__global__ void k_gatetop(const float* __restrict__ gh2,
                          const float* __restrict__ gw3, const float* __restrict__ gb3,
                          float* __restrict__ out, float* __restrict__ aux,
                          int* __restrict__ bcnt, float* __restrict__ selbuf) {
  int tid = threadIdx.x;
  int b = blockIdx.x * 256 + tid;
  int lane = tid & 63, w = tid >> 6;
  __shared__ float sprob[8];
  if (tid < 8) sprob[tid] = 0.f;
  __syncthreads();

  float lg[8];
#pragma unroll
  for (int j = 0; j < 8; ++j) lg[j] = gb3[j];
  for (int k = 0; k < 128; ++k) {
    float h = gh2[(size_t)b * 128 + k];
#pragma unroll
    for (int j = 0; j < 8; ++j) lg[j] += h * gw3[k * 8 + j];
  }
  float m = lg[0];
#pragma unroll
  for (int j = 1; j < 8; ++j) m = fmaxf(m, lg[j]);
  float probs[8], sum = 0.f;
#pragma unroll
  for (int j = 0; j < 8; ++j) { float p = expf(lg[j] - m); probs[j] = p; sum += p; }
  float inv = 1.f / sum;
#pragma unroll
  for (int j = 0; j < 8; ++j) probs[j] *= inv;
  int i0 = 0, i1;
  float v0 = -1e30f;
#pragma unroll
  for (int j = 0; j < 8; ++j) if (probs[j] > v0) { v0 = probs[j]; i0 = j; }
  float v1 = -1e30f; i1 = (i0 == 0) ? 1 : 0;
#pragma unroll
  for (int j = 0; j < 8; ++j) if (j != i0 && probs[j] > v1) { v1 = probs[j]; i1 = j; }
  float wsum = v0 + v1 + 1e-9f;
  float w0 = v0 / wsum, w1 = v1 / wsum;

  out[IDX_OFF + (size_t)b * 2 + 0] = (float)i0;
  out[IDX_OFF + (size_t)b * 2 + 1] = (float)i1;
  out[SCO_OFF + (size_t)b * 2 + 0] = v0;
  out[SCO_OFF + (size_t)b * 2 + 1] = v1;
  selbuf[(size_t)b * 4 + 0] = (float)i0;
  selbuf[(size_t)b * 4 + 1] = (float)i1;
  selbuf[(size_t)b * 4 + 2] = w0;
  selbuf[(size_t)b * 4 + 3] = w1;

#pragma unroll
  for (int e2 = 0; e2 < 8; ++e2) {
    unsigned long long mm = __ballot(i0 == e2) | __ballot(i1 == e2);
    if (lane == 0) bcnt[(blockIdx.x * 4 + w) * 8 + e2] = __popcll(mm);
  }

#pragma unroll
  for (int j = 0; j < 8; ++j) {
    float p = probs[j];
#pragma unroll
    for (int mk = 1; mk <= 32; mk <<= 1) p += __shfl_xor(p, mk, 64);
    if (lane == 0) atomicAdd(&sprob[j], p);
  }
  __syncthreads();
  if (tid < 8) atomicAdd(&aux[tid], sprob[tid]);
}

// two-level exclusive scan of bcnt (512 groups x 8 experts) -> bbase, cnt
__global__ void k_scan(const int* __restrict__ bcnt, int* __restrict__ bbase,
                       int* __restrict__ cnt) {
  __shared__ int psum[8][8]; // [seg][e2]
  int tid = threadIdx.x;
  int e2 = tid & 7, seg = tid >> 3;
  int s = 0;
  for (int i = 0; i < 64; ++i) s += bcnt[(seg * 64 + i) * 8 + e2];
  psum[seg][e2] = s;
  __syncthreads();
  int base = 0;
  for (int t = 0; t < seg; ++t) base += psum[t][e2];
  int run = base;
  for (int i = 0; i < 64; ++i) {
    bbase[(seg * 64 + i) * 8 + e2] = run;
    run += bcnt[(seg * 64 + i) * 8 + e2];
  }
  if (seg == 7) cnt[e2] = run;
}

// fill perm sorted by row within each expert (deterministic, ballot ranks)
__global__ void k_fill(const float* __restrict__ selbuf, const int* __restrict__ bbase,
                       int* __restrict__ perm) {
  int gidx = blockIdx.x;          // 512 groups
  int lane = threadIdx.x;         // 64
  int b = gidx * 64 + lane;
  int i0 = (int)selbuf[(size_t)b * 4 + 0];
  int i1 = (int)selbuf[(size_t)b * 4 + 1];
  unsigned long long lt = (1ull << lane) - 1ull;
#pragma unroll
  for (int e2 = 0; e2 < 8; ++e2) {
    unsigned long long mm = __ballot(i0 == e2) | __ballot(i1 == e2);
    if (i0 == e2 || i1 == e2) {
      int s = bbase[gidx * 8 + e2] + (int)__popcll(mm & lt);
      if (s < CAP) perm[e2 * CAP + s] = b;
    }
  }
}

__global__ void k_auxfinal(const int* __restrict__ cnt, const float* __restrict__ aux,
                           float* __restrict__ out) {
  if (threadIdx.x == 0) {
    float s = 0.f;
#pragma unroll
    for (int e = 0; e < 8; ++e) {
      float f = (float)cnt[e] / (32768.f * 2.f);
      float P = aux[e] / 32768.f;
      s += f * P;
    }
    out[AUX_OFF] = 8.f * s;
  }
}

// ------- fused expert chain: 2 layers (GEMM+ELU+LN each) in one kernel -------
// Round-13: even/odd ping-pong B queues (zero v_mov rotation; round-12's
// q0=q1;q1=qt moves were 32 v_movs ~ 64cy/step vs 80cy MFMA). s-chain bounds
// reverted to (512,4) — (512,8)'s 64-VGPR cap forced acc spill (round-12
// regression).
template<int K1, int N1, int N2, bool GATHER, bool FCHAIN>
__launch_bounds__(512, 4)
__global__ void k_chain(const unsigned short* __restrict__ A, int As,
                        const int* __restrict__ perm, const int* __restrict__ cnt,
                        const unsigned short* __restrict__ W1, const float* __restrict__ b1v,
                        const float* __restrict__ g1v, const float* __restrict__ h1v,
                        const unsigned short* __restrict__ W2, const float* __restrict__ b2v,
                        const float* __restrict__ g2v, const float* __restrict__ h2v,
                        unsigned short* __restrict__ Out, int Os, int Ocol,
                        const float* __restrict__ fw3, const float* __restrict__ fb3,
                        float* __restrict__ allout) {
  constexpr int WC1 = N1 / 8, NF1 = WC1 / 16;
  constexpr int WC2 = N2 / 8, NF2 = WC2 / 16;
  constexpr int NK1 = K1 / 64, NK2 = N1 / 64;
  constexpr int NS1 = NK1 * 2, NS2 = NK2 * 2;
  constexpr int PAN = (K1 > N1) ? K1 : N1;
  constexpr int NCH = N2 / 128;
  static_assert(NF1 >= 1 && NF2 >= 1 && K1 % 64 == 0 && N1 % 128 == 0, "shape");

  __shared__ unsigned short smP[64 * PAN];   // A1 panel -> h1 panel -> staging
  __shared__ float red[64][8][2];
  __shared__ float rowstat[64][2];

  int e = blockIdx.y;
  int count = cnt[e]; if (count > CAP) count = CAP;
  int rb = blockIdx.x * 64;
  if (rb >= count) return;

  int tid = threadIdx.x;
  int lane = tid & 63, wn = tid >> 6;
  int l15 = lane & 15, g = lane >> 4;

  // ---- stage A1 panel (64 x K1), single barrier ----
  {
    int srow = tid >> 3, schunk = tid & 7;
    int slot = rb + srow;
    size_t arow;
    if (GATHER) {
      int s = slot < count ? slot : count - 1;
      arow = (size_t)perm[e * CAP + s];
    } else {
      arow = (size_t)e * CAP + slot;
    }
    const unsigned short* aptr = A + arow * As + schunk * 8;
    int lws = srow * K1 + ((schunk ^ (srow & 7)) << 3);
    uint4 stg[NK1];
#pragma unroll
    for (int kt = 0; kt < NK1; ++kt) stg[kt] = *(const uint4*)(aptr + kt * 64);
#pragma unroll
    for (int kt = 0; kt < NK1; ++kt) *(uint4*)(&smP[lws + kt * 64]) = stg[kt];
  }

  // ---- GEMM1: acc1 = A1 @ W1 (ping-pong B queues) ----
  const unsigned short* W1e = W1 + (size_t)e * N1 * K1;
  const unsigned short* bp1[NF1];
#pragma unroll
  for (int nf = 0; nf < NF1; ++nf)
    bp1[nf] = W1e + (size_t)(wn * WC1 + nf * 16 + l15) * K1 + g * 8;

  f32x4 acc1[4][NF1] = {};
  bf16x8 qA[NF1], qB[NF1];
#pragma unroll
  for (int nf = 0; nf < NF1; ++nf) qA[nf] = *(const bf16x8*)(bp1[nf]);
  if (NS1 > 1) {
#pragma unroll
    for (int nf = 0; nf < NF1; ++nf) qB[nf] = *(const bf16x8*)(bp1[nf] + 32);
  }

  __syncthreads();

#pragma unroll
  for (int ks = 0; ks < NS1; ++ks) {
    const int kt = ks >> 1, kk = ks & 1;
    bf16x8 a4[4];
#pragma unroll
    for (int mf = 0; mf < 4; ++mf) {
      int row = mf * 16 + l15;
      int chunk = (kk * 4 + g) ^ (row & 7);
      a4[mf] = *(const bf16x8*)(&smP[row * K1 + kt * 64 + chunk * 8]);
    }
    if ((ks & 1) == 0) {
#pragma unroll
      for (int mf = 0; mf < 4; ++mf)
#pragma unroll
        for (int nf = 0; nf < NF1; ++nf)
          acc1[mf][nf] = __builtin_amdgcn_mfma_f32_16x16x32_bf16(a4[mf], qA[nf], acc1[mf][nf], 0, 0, 0);
      if (ks + 2 < NS1) {
#pragma unroll
        for (int nf = 0; nf < NF1; ++nf) qA[nf] = *(const bf16x8*)(bp1[nf] + (ks + 2) * 32);
      }
    } else {
#pragma unroll
      for (int mf = 0; mf < 4; ++mf)
#pragma unroll
        for (int nf = 0; nf < NF1; ++nf)
          acc1[mf][nf] = __builtin_amdgcn_mfma_f32_16x16x32_bf16(a4[mf], qB[nf], acc1[mf][nf], 0, 0, 0);
      if (ks + 2 < NS1) {
#pragma unroll
        for (int nf = 0; nf < NF1; ++nf) qB[nf] = *(const bf16x8*)(bp1[nf] + (ks + 2) * 32);
      }
    }
  }

  // ---- bias + ELU + LN over N1 ----
  {
    float bia[NF1], gam[NF1], bet[NF1];
#pragma unroll
    for (int nf = 0; nf < NF1; ++nf) {
      int n = wn * WC1 + nf * 16 + l15;
      bia[nf] = b1v[e * N1 + n]; gam[nf] = g1v[e * N1 + n]; bet[nf] = h1v[e * N1 + n];
    }
#pragma unroll
    for (int mf = 0; mf < 4; ++mf)
#pragma unroll
      for (int nf = 0; nf < NF1; ++nf)
#pragma unroll
        for (int r = 0; r < 4; ++r)
          acc1[mf][nf][r] = fast_elu(acc1[mf][nf][r] + bia[nf]);
#pragma unroll
    for (int mf = 0; mf < 4; ++mf)
#pragma unroll
      for (int r = 0; r < 4; ++r) {
        float s1 = 0.f, s2 = 0.f;
#pragma unroll
        for (int nf = 0; nf < NF1; ++nf) {
          float x = acc1[mf][nf][r];
          s1 += x; s2 += x * x;
        }
#pragma unroll
        for (int mk = 1; mk <= 8; mk <<= 1) {
          s1 += __shfl_xor(s1, mk, 64);
          s2 += __shfl_xor(s2, mk, 64);
        }
        if (l15 == 0) {
          int row = mf * 16 + g * 4 + r;
          red[row][wn][0] = s1;
          red[row][wn][1] = s2;
        }
      }
    __syncthreads();   // all waves done reading A1 panel
    if (tid < 64) {
      float s1 = 0.f, s2 = 0.f;
#pragma unroll
      for (int j = 0; j < 8; ++j) { s1 += red[tid][j][0]; s2 += red[tid][j][1]; }
      float mean = s1 / (float)N1;
      float var = s2 / (float)N1 - mean * mean;
      rowstat[tid][0] = mean;
      rowstat[tid][1] = rsqrtf(var + 1e-5f);
    }
    __syncthreads();
    // normalize + write h1 into panel (stride N1, same XOR swizzle)
#pragma unroll
    for (int mf = 0; mf < 4; ++mf)
#pragma unroll
      for (int r = 0; r < 4; ++r) {
        int row = mf * 16 + g * 4 + r;
        float mean = rowstat[row][0], rstd = rowstat[row][1];
#pragma unroll
        for (int nf = 0; nf < NF1; ++nf) {
          int col = wn * WC1 + nf * 16 + l15;
          float y = (acc1[mf][nf][r] - mean) * rstd * gam[nf] + bet[nf];
          int pos = (col & ~63) + ((((col >> 3) & 7) ^ (row & 7)) << 3) + (col & 7);
          smP[row * N1 + pos] = f2b(y);
        }
      }
  }

  // ---- GEMM2: acc2 = h1 @ W2 (ping-pong B queues) ----
  const unsigned short* W2e = W2 + (size_t)e * N2 * N1;
  const unsigned short* bp2[NF2];
#pragma unroll
  for (int nf = 0; nf < NF2; ++nf)
    bp2[nf] = W2e + (size_t)(wn * WC2 + nf * 16 + l15) * N1 + g * 8;

  f32x4 acc2[4][NF2] = {};
  bf16x8 pA[NF2], pB[NF2];
#pragma unroll
  for (int nf = 0; nf < NF2; ++nf) pA[nf] = *(const bf16x8*)(bp2[nf]);
  if (NS2 > 1) {
#pragma unroll
    for (int nf = 0; nf < NF2; ++nf) pB[nf] = *(const bf16x8*)(bp2[nf] + 32);
  }

  __syncthreads();   // h1 panel complete

#pragma unroll
  for (int ks = 0; ks < NS2; ++ks) {
    const int kt = ks >> 1, kk = ks & 1;
    bf16x8 a4[4];
#pragma unroll
    for (int mf = 0; mf < 4; ++mf) {
      int row = mf * 16 + l15;
      int chunk = (kk * 4 + g) ^ (row & 7);
      a4[mf] = *(const bf16x8*)(&smP[row * N1 + kt * 64 + chunk * 8]);
    }
    if ((ks & 1) == 0) {
#pragma unroll
      for (int mf = 0; mf < 4; ++mf)
#pragma unroll
        for (int nf = 0; nf < NF2; ++nf)
          acc2[mf][nf] = __builtin_amdgcn_mfma_f32_16x16x32_bf16(a4[mf], pA[nf], acc2[mf][nf], 0, 0, 0);
      if (ks + 2 < NS2) {
#pragma unroll
        for (int nf = 0; nf < NF2; ++nf) pA[nf] = *(const bf16x8*)(bp2[nf] + (ks + 2) * 32);
      }
    } else {
#pragma unroll
      for (int mf = 0; mf < 4; ++mf)
#pragma unroll
        for (int nf = 0; nf < NF2; ++nf)
          acc2[mf][nf] = __builtin_amdgcn_mfma_f32_16x16x32_bf16(a4[mf], pB[nf], acc2[mf][nf], 0, 0, 0);
      if (ks + 2 < NS2) {
#pragma unroll
        for (int nf = 0; nf < NF2; ++nf) pB[nf] = *(const bf16x8*)(bp2[nf] + (ks + 2) * 32);
      }
    }
  }

  // ---- bias + ELU + LN over N2 ----
  {
    float bia[NF2], gam[NF2], bet[NF2];
#pragma unroll
    for (int nf = 0; nf < NF2; ++nf) {
      int n = wn * WC2 + nf * 16 + l15;
      bia[nf] = b2v[e * N2 + n]; gam[nf] = g2v[e * N2 + n]; bet[nf] = h2v[e * N2 + n];
    }
#pragma unroll
    for (int mf = 0; mf < 4; ++mf)
#pragma unroll
      for (int nf = 0; nf < NF2; ++nf)
#pragma unroll
        for (int r = 0; r < 4; ++r)
          acc2[mf][nf][r] = fast_elu(acc2[mf][nf][r] + bia[nf]);
#pragma unroll
    for (int mf = 0; mf < 4; ++mf)
#pragma unroll
      for (int r = 0; r < 4; ++r) {
        float s1 = 0.f, s2 = 0.f;
#pragma unroll
        for (int nf = 0; nf < NF2; ++nf) {
          float x = acc2[mf][nf][r];
          s1 += x; s2 += x * x;
        }
#pragma unroll
        for (int mk = 1; mk <= 8; mk <<= 1) {
          s1 += __shfl_xor(s1, mk, 64);
          s2 += __shfl_xor(s2, mk, 64);
        }
        if (l15 == 0) {
          int row = mf * 16 + g * 4 + r;
          red[row][wn][0] = s1;
          red[row][wn][1] = s2;
        }
      }
    __syncthreads();   // all waves done reading h1 panel
    if (tid < 64) {
      float s1 = 0.f, s2 = 0.f;
#pragma unroll
      for (int j = 0; j < 8; ++j) { s1 += red[tid][j][0]; s2 += red[tid][j][1]; }
      float mean = s1 / (float)N2;
      float var = s2 / (float)N2 - mean * mean;
      rowstat[tid][0] = mean;
      rowstat[tid][1] = rsqrtf(var + 1e-5f);
    }
    __syncthreads();
#pragma unroll
    for (int mf = 0; mf < 4; ++mf)
#pragma unroll
      for (int r = 0; r < 4; ++r) {
        int row = mf * 16 + g * 4 + r;
        float mean = rowstat[row][0], rstd = rowstat[row][1];
#pragma unroll
        for (int nf = 0; nf < NF2; ++nf)
          acc2[mf][nf][r] = (acc2[mf][nf][r] - mean) * rstd * gam[nf] + bet[nf];
      }
  }

  if constexpr (!FCHAIN) {
    // ---- vectorized store via LDS staging, 128-col chunks ----
    unsigned short* sm16 = &smP[0];       // [64][128]
    int wq = (wn * WC2) >> 7;
    for (int q = 0; q < NCH; ++q) {
      __syncthreads();
      if (NCH == 1 || wq == q) {
#pragma unroll
        for (int mf = 0; mf < 4; ++mf)
#pragma unroll
          for (int r = 0; r < 4; ++r) {
            int row = mf * 16 + g * 4 + r;
            int s = row & 7;
#pragma unroll
            for (int nf = 0; nf < NF2; ++nf) {
              int lc = (wn * WC2 + nf * 16 + l15) - q * 128;   // 0..127
              if (NCH == 1 || (lc >= 0 && lc < 128)) {
                int pos = (((lc >> 3) ^ s) << 3) | (lc & 7);
                sm16[row * 128 + pos] = f2b(acc2[mf][nf][r]);
              }
            }
          }
      }
      __syncthreads();
#pragma unroll
      for (int i = 0; i < 2; ++i) {
        int t = tid + i * 512;
        int row = t >> 4, cc = t & 15;
        int oc = cc ^ (row & 7);
        uint4 v = *(const uint4*)(&sm16[row * 128 + cc * 8]);
        *(uint4*)(&Out[((size_t)e * CAP + rb + row) * Os + Ocol + q * 128 + oc * 8]) = v;
      }
    }
  } else {
    // ---- f-chain: h2 to LDS (padded) + fw3 staged to LDS, 256->12 head ----
    __syncthreads();   // acc2 final everywhere; panel free
    constexpr int H2S = 264;  // row stride (pad 8 to break bank alignment)
    float* wsh = (float*)(&smP[64 * H2S]);   // 12 KB, disjoint from h2 rows
#pragma unroll
    for (int mf = 0; mf < 4; ++mf)
#pragma unroll
      for (int r = 0; r < 4; ++r) {
        int row = mf * 16 + g * 4 + r;
#pragma unroll
        for (int nf = 0; nf < NF2; ++nf) {
          int col = wn * WC2 + nf * 16 + l15;
          smP[row * H2S + col] = f2b(acc2[mf][nf][r]);
        }
      }
    for (int i = tid; i < 256 * 12; i += 512) wsh[i] = fw3[(size_t)e * 256 * 12 + i];
    __syncthreads();
#pragma unroll
    for (int it = 0; it < 2; ++it) {
      int idx = tid + it * 512;
      if (idx < 768) {
        int row = idx / 12, j = idx - row * 12;
        int slot2 = rb + row;
        if (slot2 < count) {
          float a = fb3[e * 12 + j];
          for (int c = 0; c < 256; ++c)
            a += b2f(smP[row * H2S + c]) * wsh[c * 12 + j];
          int arow = perm[e * CAP + slot2];
          allout[((size_t)arow * 8 + e) * 12 + j] = a;
        }
      }
    }
  }
}

// ------- mix: weighted sum of the two selected expert outputs -------
__global__ void k_mix(const float* __restrict__ selbuf, const float* __restrict__ allout,
                      float* __restrict__ out) {
  int b = blockIdx.x * 256 + threadIdx.x;
  int i0 = (int)selbuf[(size_t)b * 4 + 0];
  int i1 = (int)selbuf[(size_t)b * 4 + 1];
  float w0 = selbuf[(size_t)b * 4 + 2];
  float w1 = selbuf[(size_t)b * 4 + 3];
  const float* a0 = allout + ((size_t)b * 8 + i0) * 12;
  const float* a1 = allout + ((size_t)b * 8 + i1) * 12;
#pragma unroll
  for (int j = 0; j < 12; ++j)
    out[(size_t)b * 12 + j] = w0 * a0[j] + w1 * a1[j];
}

// ---------------- host ----------------

extern "C" void kernel_launch(void* const* d_in, const int* in_sizes, int n_in,
                              void* d_out, int out_size, void* d_ws, size_t ws_size,
                              hipStream_t stream) {
  const float* state = (const float*)d_in[0];
  const float* vlm   = (const float*)d_in[1];
  const float* sw1 = (const float*)d_in[2];  const float* sb1 = (const float*)d_in[3];
  const float* sg1 = (const float*)d_in[4];  const float* sh1 = (const float*)d_in[5];
  const float* sw2 = (const float*)d_in[6];  const float* sb2 = (const float*)d_in[7];
  const float* sg2 = (const float*)d_in[8];  const float* sh2 = (const float*)d_in[9];
  const float* vw1 = (const float*)d_in[10]; const float* vb1 = (const float*)d_in[11];
  const float* vg1 = (const float*)d_in[12]; const float* vh1 = (const float*)d_in[13];
  const float* vw2 = (const float*)d_in[14]; const float* vb2 = (const float*)d_in[15];
  const float* vg2 = (const float*)d_in[16]; const float* vh2 = (const float*)d_in[17];
  const float* fw1 = (const float*)d_in[18]; const float* fb1 = (const float*)d_in[19];
  const float* fg1 = (const float*)d_in[20]; const float* fh1 = (const float*)d_in[21];
  const float* fw2 = (const float*)d_in[22]; const float* fb2 = (const float*)d_in[23];
  const float* fg2 = (const float*)d_in[24]; const float* fh2 = (const float*)d_in[25];
  const float* fw3 = (const float*)d_in[26]; const float* fb3 = (const float*)d_in[27];
  const float* gw1 = (const float*)d_in[28]; const float* gb1 = (const float*)d_in[29];
  const float* gw2 = (const float*)d_in[30]; const float* gb2 = (const float*)d_in[31];
  const float* gw3 = (const float*)d_in[32]; const float* gb3 = (const float*)d_in[33];

  // ---- workspace (~182 MB) ----
  char* ws = (char*)d_ws;
  size_t off = 0;
  auto alloc = [&](size_t bytes) -> char* {
    char* p = ws + off;
    off = (off + bytes + 255) & ~(size_t)255;
    return p;
  };
  unsigned short* st_bf = (unsigned short*)alloc((size_t)BROWS * 128 * 2);      // 8.4 MB
  unsigned short* vl_bf = (unsigned short*)alloc((size_t)BROWS * 512 * 2);      // 33.6 MB
  unsigned short* bufF  = (unsigned short*)alloc((size_t)NEXP * CAP * 384 * 2); // 62.9 MB
  float* allout = (float*)alloc((size_t)BROWS * 8 * 12 * 4);                    // 12.6 MB
  float* gh1    = (float*)alloc((size_t)BROWS * 256 * 4);                       // 33.6 MB
  float* gh2    = (float*)alloc((size_t)BROWS * 128 * 4);                       // 16.8 MB
  float* selbuf = (float*)alloc((size_t)BROWS * 4 * 4);
  int*   perm   = (int*)alloc((size_t)NEXP * CAP * 4);
  int*   bcnt   = (int*)alloc(512 * 8 * 4);
  int*   bbase  = (int*)alloc(512 * 8 * 4);
  char*  cntaux = alloc(256);  // cnt: 8 ints at +0, aux: 8 floats at +64
  int*   cnt = (int*)cntaux;
  float* aux = (float*)(cntaux + 64);
  unsigned short* wt_s1 = (unsigned short*)alloc((size_t)8 * 256 * 128 * 2);
  unsigned short* wt_s2 = (unsigned short*)alloc((size_t)8 * 128 * 256 * 2);
  unsigned short* wt_v1 = (unsigned short*)alloc((size_t)8 * 512 * 512 * 2);
  unsigned short* wt_v2 = (unsigned short*)alloc((size_t)8 * 256 * 512 * 2);
  unsigned short* wt_f1 = (unsigned short*)alloc((size_t)8 * 512 * 384 * 2);
  unsigned short* wt_f2 = (unsigned short*)alloc((size_t)8 * 256 * 512 * 2);
  (void)ws_size; (void)in_sizes; (void)n_in; (void)out_size;

  float* outf = (float*)d_out;

  // prep
  k_convert_pad<<<(BROWS * 128 + 255) / 256, 256, 0, stream>>>(state, st_bf, BROWS, 96, 128);
  k_convert_pad<<<(BROWS * 512 + 255) / 256, 256, 0, stream>>>(vlm, vl_bf, BROWS, 512, 512);
  k_wtrans<<<dim3(4, 8, 8),   dim3(32, 8), 0, stream>>>(sw1, wt_s1, 96, 256, 128);
  k_wtrans<<<dim3(8, 4, 8),   dim3(32, 8), 0, stream>>>(sw2, wt_s2, 256, 128, 256);
  k_wtrans<<<dim3(16, 16, 8), dim3(32, 8), 0, stream>>>(vw1, wt_v1, 512, 512, 512);
  k_wtrans<<<dim3(16, 8, 8),  dim3(32, 8), 0, stream>>>(vw2, wt_v2, 512, 256, 512);
  k_wtrans<<<dim3(12, 16, 8), dim3(32, 8), 0, stream>>>(fw1, wt_f1, 384, 512, 384);
  k_wtrans<<<dim3(16, 8, 8),  dim3(32, 8), 0, stream>>>(fw2, wt_f2, 512, 256, 512);
  k_zero<<<1, 64, 0, stream>>>((int*)cntaux, 64);

  // gate (fp32 for exact top-k)
  k_gemm32<true><<<dim3(256, 2), 256, 0, stream>>>(state, 96, vlm, 512, 96,
                                                   gw1, gb1, 608, 256, gh1);
  k_gemm32<false><<<dim3(256, 1), 256, 0, stream>>>(gh1, 256, nullptr, 0, 0,
                                                    gw2, gb2, 256, 128, gh2);
  k_gatetop<<<BROWS / 256, 256, 0, stream>>>(gh2, gw3, gb3, outf, aux, bcnt, selbuf);
  k_scan<<<1, 64, 0, stream>>>(bcnt, bbase, cnt);
  k_fill<<<512, 64, 0, stream>>>(selbuf, bbase, perm);
  k_auxfinal<<<1, 64, 0, stream>>>(cnt, aux, outf);

  // fused expert chains
  dim3 lg(CAPBLK, NEXP);
  // s-chain: st_bf -> 256 -> 128 -> bufF[:, 0:128]
  k_chain<128, 256, 128, true, false><<<lg, 512, 0, stream>>>(
      st_bf, 128, perm, cnt,
      wt_s1, sb1, sg1, sh1, wt_s2, sb2, sg2, sh2,
      bufF, 384, 0, nullptr, nullptr, nullptr);
  // v-chain: vl_bf -> 512 -> 256 -> bufF[:, 128:384]
  k_chain<512, 512, 256, true, false><<<lg, 512, 0, stream>>>(
      vl_bf, 512, perm, cnt,
      wt_v1, vb1, vg1, vh1, wt_v2, vb2, vg2, vh2,
      bufF, 384, 128, nullptr, nullptr, nullptr);
  // f-chain: bufF -> 512 -> 256 -> head 12 -> allout
  k_chain<384, 512, 256, false, true><<<lg, 512, 0, stream>>>(
      bufF, 384, perm, cnt,
      wt_f1, fb1, fg1, fh1, wt_f2, fb2, fg2, fh2,
      nullptr, 0, 0, fw3, fb3, allout);

  k_mix<<<BROWS / 256, 256, 0, stream>>>(selbuf, allout, outf);
}

// Round 14
// 621.128 us; speedup vs baseline: 1.0908x; 1.0119x over previous
//
#include <hip/hip_runtime.h>
#include <cstdint>
#include <cstddef>

#define BROWS 32768
#define NEXP 8
#define CAP 10240          // per-expert row capacity (E[count]=8192, std~78)
#define CAPBLK (CAP / 64)

typedef short bf16x8 __attribute__((ext_vector_type(8)));
typedef float f32x4 __attribute__((ext_vector_type(4)));

__device__ __forceinline__ unsigned short f2b(float f) {
  union { float f; unsigned u; } v; v.f = f;
  unsigned r = (v.u + 0x7fffu + ((v.u >> 16) & 1u)) >> 16;
  return (unsigned short)r;
}
__device__ __forceinline__ float b2f(unsigned short s) {
  union { unsigned u; float f; } v; v.u = ((unsigned)s) << 16; return v.f;
}
// Fast ELU for the bf16 expert path (round-11 win: 211->175us on v-chain).
__device__ __forceinline__ float fast_elu(float x) {
  return x > 0.f ? x : __expf(x) - 1.f;
}

// ---------------- prep kernels ----------------

__global__ void k_convert_pad(const float* __restrict__ src, unsigned short* __restrict__ dst,
                              int rows, int sc, int dc) {
  int i = blockIdx.x * 256 + threadIdx.x;
  if (i >= rows * dc) return;
  int r = i / dc, c = i % dc;
  float v = (c < sc) ? src[(size_t)r * sc + c] : 0.f;
  dst[i] = f2b(v);
}

// src f32 [E][K][N] -> dst bf16 [E][N][Kpad]
__global__ void k_wtrans(const float* __restrict__ src, unsigned short* __restrict__ dst,
                         int K, int N, int Kpad) {
  __shared__ float tile[32][33];
  int e = blockIdx.z;
  int k0 = blockIdx.x * 32, n0 = blockIdx.y * 32;
  int tx = threadIdx.x, ty = threadIdx.y; // 32 x 8
  for (int i = 0; i < 32; i += 8) {
    int k = k0 + ty + i;
    tile[ty + i][tx] = (k < K) ? src[((size_t)e * K + k) * N + n0 + tx] : 0.f;
  }
  __syncthreads();
  for (int i = 0; i < 32; i += 8) {
    int n = n0 + ty + i;
    dst[((size_t)e * N + n) * Kpad + k0 + tx] = f2b(tile[tx][ty + i]);
  }
}

__global__ void k_zero(int* p, int n) {
  int i = blockIdx.x * 64 + threadIdx.x;
  if (i < n) p[i] = 0;
}

// ---------------- fp32 gate GEMM: Out = ELU(A@W + bias) ----------------
// 128x128 tile, 256 thr, 8x8 micro-tile, named regs, bounds (256,4).
template<bool TWOSRC>
__launch_bounds__(256, 4)
__global__ void k_gemm32(const float* __restrict__ A0, int As0,
                         const float* __restrict__ A1, int As1, int Ks,
                         const float* __restrict__ W, const float* __restrict__ bias,
                         int K, int N, float* __restrict__ Out) {
  __shared__ float At[32][132];
  __shared__ float Bs[32][132];

  int tid = threadIdx.x;
  int rb = blockIdx.x * 128, nb = blockIdx.y * 128;
  int tx = tid & 15, tyg = tid >> 4;
  int arow = tid >> 1, aq = (tid & 1) * 16;
  int brow = tid >> 3, bc = (tid & 7) * 16;

  f32x4 c0a = {0,0,0,0}, c0b = {0,0,0,0}, c1a = {0,0,0,0}, c1b = {0,0,0,0};
  f32x4 c2a = {0,0,0,0}, c2b = {0,0,0,0}, c3a = {0,0,0,0}, c3b = {0,0,0,0};
  f32x4 c4a = {0,0,0,0}, c4b = {0,0,0,0}, c5a = {0,0,0,0}, c5b = {0,0,0,0};
  f32x4 c6a = {0,0,0,0}, c6b = {0,0,0,0}, c7a = {0,0,0,0}, c7b = {0,0,0,0};

  float4 a0, a1, a2, a3, b0, b1, b2, b3;
  {
    const float* arp = (!TWOSRC || aq < Ks)
        ? (A0 + (size_t)(rb + arow) * As0 + aq)
        : (A1 + (size_t)(rb + arow) * As1 + (aq - Ks));
    a0 = *(const float4*)(arp);
    a1 = *(const float4*)(arp + 4);
    a2 = *(const float4*)(arp + 8);
    a3 = *(const float4*)(arp + 12);
    const float* brp = W + (size_t)brow * N + nb + bc;
    b0 = *(const float4*)(brp);
    b1 = *(const float4*)(brp + 4);
    b2 = *(const float4*)(brp + 8);
    b3 = *(const float4*)(brp + 12);
  }

  const int NT = K / 32;
  for (int kt = 0; kt < NT; ++kt) {
    __syncthreads();
    At[aq + 0][arow] = a0.x;  At[aq + 1][arow] = a0.y;
    At[aq + 2][arow] = a0.z;  At[aq + 3][arow] = a0.w;
    At[aq + 4][arow] = a1.x;  At[aq + 5][arow] = a1.y;
    At[aq + 6][arow] = a1.z;  At[aq + 7][arow] = a1.w;
    At[aq + 8][arow] = a2.x;  At[aq + 9][arow] = a2.y;
    At[aq + 10][arow] = a2.z; At[aq + 11][arow] = a2.w;
    At[aq + 12][arow] = a3.x; At[aq + 13][arow] = a3.y;
    At[aq + 14][arow] = a3.z; At[aq + 15][arow] = a3.w;
    *(float4*)(&Bs[brow][bc])      = b0;
    *(float4*)(&Bs[brow][bc + 4])  = b1;
    *(float4*)(&Bs[brow][bc + 8])  = b2;
    *(float4*)(&Bs[brow][bc + 12]) = b3;
    __syncthreads();

    if (kt + 1 < NT) {
      int ka = (kt + 1) * 32 + aq;
      const float* arp = (!TWOSRC || ka < Ks)
          ? (A0 + (size_t)(rb + arow) * As0 + ka)
          : (A1 + (size_t)(rb + arow) * As1 + (ka - Ks));
      a0 = *(const float4*)(arp);
      a1 = *(const float4*)(arp + 4);
      a2 = *(const float4*)(arp + 8);
      a3 = *(const float4*)(arp + 12);
      const float* brp = W + (size_t)((kt + 1) * 32 + brow) * N + nb + bc;
      b0 = *(const float4*)(brp);
      b1 = *(const float4*)(brp + 4);
      b2 = *(const float4*)(brp + 8);
      b3 = *(const float4*)(brp + 12);
    }

#pragma unroll 4
    for (int kk = 0; kk < 32; ++kk) {
      float4 av0 = *(const float4*)(&At[kk][tyg * 8]);
      float4 av1 = *(const float4*)(&At[kk][tyg * 8 + 4]);
      f32x4 bva = *(const f32x4*)(&Bs[kk][tx * 8]);
      f32x4 bvb = *(const f32x4*)(&Bs[kk][tx * 8 + 4]);
      c0a += bva * av0.x; c0b += bvb * av0.x;
      c1a += bva * av0.y; c1b += bvb * av0.y;
      c2a += bva * av0.z; c2b += bvb * av0.z;
      c3a += bva * av0.w; c3b += bvb * av0.w;
      c4a += bva * av1.x; c4b += bvb * av1.x;
      c5a += bva * av1.y; c5b += bvb * av1.y;
      c6a += bva * av1.z; c6b += bvb * av1.z;
      c7a += bva * av1.w; c7b += bvb * av1.w;
    }
  }

  float4 bia0 = *(const float4*)(&bias[nb + tx * 8]);
  float4 bia1 = *(const float4*)(&bias[nb + tx * 8 + 4]);

#define GEMM_STORE_ROW(ACA, ACB, I)                                          \
  {                                                                          \
    float o0 = ACA[0] + bia0.x, o1 = ACA[1] + bia0.y;                        \
    float o2 = ACA[2] + bia0.z, o3 = ACA[3] + bia0.w;                        \
    float o4 = ACB[0] + bia1.x, o5 = ACB[1] + bia1.y;                        \
    float o6 = ACB[2] + bia1.z, o7 = ACB[3] + bia1.w;                        \
    o0 = (o0 > 0.f) ? o0 : expm1f(o0); o1 = (o1 > 0.f) ? o1 : expm1f(o1);    \
    o2 = (o2 > 0.f) ? o2 : expm1f(o2); o3 = (o3 > 0.f) ? o3 : expm1f(o3);    \
    o4 = (o4 > 0.f) ? o4 : expm1f(o4); o5 = (o5 > 0.f) ? o5 : expm1f(o5);    \
    o6 = (o6 > 0.f) ? o6 : expm1f(o6); o7 = (o7 > 0.f) ? o7 : expm1f(o7);    \
    float4 w0; w0.x = o0; w0.y = o1; w0.z = o2; w0.w = o3;                   \
    float4 w1; w1.x = o4; w1.y = o5; w1.z = o6; w1.w = o7;                   \
    size_t orow = (size_t)(rb + tyg * 8 + (I)) * N + nb + tx * 8;            \
    *(float4*)(&Out[orow]) = w0;                                             \
    *(float4*)(&Out[orow + 4]) = w1;                                         \
  }
  GEMM_STORE_ROW(c0a, c0b, 0)
  GEMM_STORE_ROW(c1a, c1b, 1)
  GEMM_STORE_ROW(c2a, c2b, 2)
  GEMM_STORE_ROW(c3a, c3b, 3)
  GEMM_STORE_ROW(c4a, c4b, 4)
  GEMM_STORE_ROW(c5a, c5b, 5)
  GEMM_STORE_ROW(c6a, c6b, 6)
  GEMM_STORE_ROW(c7a, c7b, 7)
#undef GEMM_STORE_ROW
}

// ------- gate head: logits, softmax, top-2; per-wave-group counts -------
#define ACTION_SZ (32768 * 12)
#define AUX_OFF   ACTION_SZ
#define IDX_OFF   (ACTION_SZ + 1)
#define SCO_OFF   (ACTION_SZ + 1 + 32768 * 2)

__global__ void k_gatetop(const float* __restrict__ gh2,
                          const float* __restrict__ gw3, const float* __restrict__ gb3,
                          float* __restrict__ out, float* __restrict__ aux,
                          int* __restrict__ bcnt, float* __restrict__ selbuf) {
  int tid = threadIdx.x;
  int b = blockIdx.x * 256 + tid;
  int lane = tid & 63, w = tid >> 6;
  __shared__ float sprob[8];
  if (tid < 8) sprob[tid] = 0.f;
  __syncthreads();

  float lg[8];
#pragma unroll
  for (int j = 0; j < 8; ++j) lg[j] = gb3[j];
  for (int k = 0; k < 128; ++k) {
    float h = gh2[(size_t)b * 128 + k];
#pragma unroll
    for (int j = 0; j < 8; ++j) lg[j] += h * gw3[k * 8 + j];
  }
  float m = lg[0];
#pragma unroll
  for (int j = 1; j < 8; ++j) m = fmaxf(m, lg[j]);
  float probs[8], sum = 0.f;
#pragma unroll
  for (int j = 0; j < 8; ++j) { float p = expf(lg[j] - m); probs[j] = p; sum += p; }
  float inv = 1.f / sum;
#pragma unroll
  for (int j = 0; j < 8; ++j) probs[j] *= inv;
  int i0 = 0, i1;
  float v0 = -1e30f;
#pragma unroll
  for (int j = 0; j < 8; ++j) if (probs[j] > v0) { v0 = probs[j]; i0 = j; }
  float v1 = -1e30f; i1 = (i0 == 0) ? 1 : 0;
#pragma unroll
  for (int j = 0; j < 8; ++j) if (j != i0 && probs[j] > v1) { v1 = probs[j]; i1 = j; }
  float wsum = v0 + v1 + 1e-9f;
  float w0 = v0 / wsum, w1 = v1 / wsum;

  out[IDX_OFF + (size_t)b * 2 + 0] = (float)i0;
  out[IDX_OFF + (size_t)b * 2 + 1] = (float)i1;
  out[SCO_OFF + (size_t)b * 2 + 0] = v0;
  out[SCO_OFF + (size_t)b * 2 + 1] = v1;
  selbuf[(size_t)b * 4 + 0] = (float)i0;
  selbuf[(size_t)b * 4 + 1] = (float)i1;
  selbuf[(size_t)b * 4 + 2] = w0;
  selbuf[(size_t)b * 4 + 3] = w1;

#pragma unroll
  for (int e2 = 0; e2 < 8; ++e2) {
    unsigned long long mm = __ballot(i0 == e2) | __ballot(i1 == e2);
    if (lane == 0) bcnt[(blockIdx.x * 4 + w) * 8 + e2] = __popcll(mm);
  }

#pragma unroll
  for (int j = 0; j < 8; ++j) {
    float p = probs[j];
#pragma unroll
    for (int mk = 1; mk <= 32; mk <<= 1) p += __shfl_xor(p, mk, 64);
    if (lane == 0) atomicAdd(&sprob[j], p);
  }
  __syncthreads();
  if (tid < 8) atomicAdd(&aux[tid], sprob[tid]);
}

// two-level exclusive scan of bcnt (512 groups x 8 experts) -> bbase, cnt
__global__ void k_scan(const int* __restrict__ bcnt, int* __restrict__ bbase,
                       int* __restrict__ cnt) {
  __shared__ int psum[8][8]; // [seg][e2]
  int tid = threadIdx.x;
  int e2 = tid & 7, seg = tid >> 3;
  int s = 0;
  for (int i = 0; i < 64; ++i) s += bcnt[(seg * 64 + i) * 8 + e2];
  psum[seg][e2] = s;
  __syncthreads();
  int base = 0;
  for (int t = 0; t < seg; ++t) base += psum[t][e2];
  int run = base;
  for (int i = 0; i < 64; ++i) {
    bbase[(seg * 64 + i) * 8 + e2] = run;
    run += bcnt[(seg * 64 + i) * 8 + e2];
  }
  if (seg == 7) cnt[e2] = run;
}

// fill perm sorted by row within each expert (deterministic, ballot ranks)
__global__ void k_fill(const float* __restrict__ selbuf, const int* __restrict__ bbase,
                       int* __restrict__ perm) {
  int gidx = blockIdx.x;          // 512 groups
  int lane = threadIdx.x;         // 64
  int b = gidx * 64 + lane;
  int i0 = (int)selbuf[(size_t)b * 4 + 0];
  int i1 = (int)selbuf[(size_t)b * 4 + 1];
  unsigned long long lt = (1ull << lane) - 1ull;
#pragma unroll
  for (int e2 = 0; e2 < 8; ++e2) {
    unsigned long long mm = __ballot(i0 == e2) | __ballot(i1 == e2);
    if (i0 == e2 || i1 == e2) {
      int s = bbase[gidx * 8 + e2] + (int)__popcll(mm & lt);
      if (s < CAP) perm[e2 * CAP + s] = b;
    }
  }
}

__global__ void k_auxfinal(const int* __restrict__ cnt, const float* __restrict__ aux,
                           float* __restrict__ out) {
  if (threadIdx.x == 0) {
    float s = 0.f;
#pragma unroll
    for (int e = 0; e < 8; ++e) {
      float f = (float)cnt[e] / (32768.f * 2.f);
      float P = aux[e] / 32768.f;
      s += f * P;
    }
    out[AUX_OFF] = 8.f * s;
  }
}

// ------- fused expert chain: 2 layers (GEMM+ELU+LN each) in one kernel -------
// Round-14: expert->XCD pinning. 1D grid, e = bid & 7: under round-robin
// workgroup dispatch each XCD gets ONE expert's blocks, so its 4MB L2 holds
// that expert's W1+W2 (<=896KB) instead of thrashing on all 8 experts' 6MB
// (round-13 diagnosis: B loads from L3/HBM ~600-900cy >> 160cy prefetch
// cover -> 65% idle). Perf-only heuristic; correctness mapping-independent.
template<int K1, int N1, int N2, bool GATHER, bool FCHAIN>
__launch_bounds__(512, 4)
__global__ void k_chain(const unsigned short* __restrict__ A, int As,
                        const int* __restrict__ perm, const int* __restrict__ cnt,
                        const unsigned short* __restrict__ W1, const float* __restrict__ b1v,
                        const float* __restrict__ g1v, const float* __restrict__ h1v,
                        const unsigned short* __restrict__ W2, const float* __restrict__ b2v,
                        const float* __restrict__ g2v, const float* __restrict__ h2v,
                        unsigned short* __restrict__ Out, int Os, int Ocol,
                        const float* __restrict__ fw3, const float* __restrict__ fb3,
                        float* __restrict__ allout) {
  constexpr int WC1 = N1 / 8, NF1 = WC1 / 16;
  constexpr int WC2 = N2 / 8, NF2 = WC2 / 16;
  constexpr int NK1 = K1 / 64, NK2 = N1 / 64;
  constexpr int NS1 = NK1 * 2, NS2 = NK2 * 2;
  constexpr int PAN = (K1 > N1) ? K1 : N1;
  constexpr int NCH = N2 / 128;
  static_assert(NF1 >= 1 && NF2 >= 1 && K1 % 64 == 0 && N1 % 128 == 0, "shape");

  __shared__ unsigned short smP[64 * PAN];   // A1 panel -> h1 panel -> staging
  __shared__ float red[64][8][2];
  __shared__ float rowstat[64][2];

  int bid = blockIdx.x;
  int e = bid & 7;              // expert = bid % NXCD -> one expert per XCD
  int count = cnt[e]; if (count > CAP) count = CAP;
  int rb = (bid >> 3) * 64;
  if (rb >= count) return;

  int tid = threadIdx.x;
  int lane = tid & 63, wn = tid >> 6;
  int l15 = lane & 15, g = lane >> 4;

  // ---- stage A1 panel (64 x K1), single barrier ----
  {
    int srow = tid >> 3, schunk = tid & 7;
    int slot = rb + srow;
    size_t arow;
    if (GATHER) {
      int s = slot < count ? slot : count - 1;
      arow = (size_t)perm[e * CAP + s];
    } else {
      arow = (size_t)e * CAP + slot;
    }
    const unsigned short* aptr = A + arow * As + schunk * 8;
    int lws = srow * K1 + ((schunk ^ (srow & 7)) << 3);
    uint4 stg[NK1];
#pragma unroll
    for (int kt = 0; kt < NK1; ++kt) stg[kt] = *(const uint4*)(aptr + kt * 64);
#pragma unroll
    for (int kt = 0; kt < NK1; ++kt) *(uint4*)(&smP[lws + kt * 64]) = stg[kt];
  }

  // ---- GEMM1: acc1 = A1 @ W1 (ping-pong B queues) ----
  const unsigned short* W1e = W1 + (size_t)e * N1 * K1;
  const unsigned short* bp1[NF1];
#pragma unroll
  for (int nf = 0; nf < NF1; ++nf)
    bp1[nf] = W1e + (size_t)(wn * WC1 + nf * 16 + l15) * K1 + g * 8;

  f32x4 acc1[4][NF1] = {};
  bf16x8 qA[NF1], qB[NF1];
#pragma unroll
  for (int nf = 0; nf < NF1; ++nf) qA[nf] = *(const bf16x8*)(bp1[nf]);
  if (NS1 > 1) {
#pragma unroll
    for (int nf = 0; nf < NF1; ++nf) qB[nf] = *(const bf16x8*)(bp1[nf] + 32);
  }

  __syncthreads();

#pragma unroll
  for (int ks = 0; ks < NS1; ++ks) {
    const int kt = ks >> 1, kk = ks & 1;
    bf16x8 a4[4];
#pragma unroll
    for (int mf = 0; mf < 4; ++mf) {
      int row = mf * 16 + l15;
      int chunk = (kk * 4 + g) ^ (row & 7);
      a4[mf] = *(const bf16x8*)(&smP[row * K1 + kt * 64 + chunk * 8]);
    }
    if ((ks & 1) == 0) {
#pragma unroll
      for (int mf = 0; mf < 4; ++mf)
#pragma unroll
        for (int nf = 0; nf < NF1; ++nf)
          acc1[mf][nf] = __builtin_amdgcn_mfma_f32_16x16x32_bf16(a4[mf], qA[nf], acc1[mf][nf], 0, 0, 0);
      if (ks + 2 < NS1) {
#pragma unroll
        for (int nf = 0; nf < NF1; ++nf) qA[nf] = *(const bf16x8*)(bp1[nf] + (ks + 2) * 32);
      }
    } else {
#pragma unroll
      for (int mf = 0; mf < 4; ++mf)
#pragma unroll
        for (int nf = 0; nf < NF1; ++nf)
          acc1[mf][nf] = __builtin_amdgcn_mfma_f32_16x16x32_bf16(a4[mf], qB[nf], acc1[mf][nf], 0, 0, 0);
      if (ks + 2 < NS1) {
#pragma unroll
        for (int nf = 0; nf < NF1; ++nf) qB[nf] = *(const bf16x8*)(bp1[nf] + (ks + 2) * 32);
      }
    }
  }

  // ---- bias + ELU + LN over N1 ----
  {
    float bia[NF1], gam[NF1], bet[NF1];
#pragma unroll
    for (int nf = 0; nf < NF1; ++nf) {
      int n = wn * WC1 + nf * 16 + l15;
      bia[nf] = b1v[e * N1 + n]; gam[nf] = g1v[e * N1 + n]; bet[nf] = h1v[e * N1 + n];
    }
#pragma unroll
    for (int mf = 0; mf < 4; ++mf)
#pragma unroll
      for (int nf = 0; nf < NF1; ++nf)
#pragma unroll
        for (int r = 0; r < 4; ++r)
          acc1[mf][nf][r] = fast_elu(acc1[mf][nf][r] + bia[nf]);
#pragma unroll
    for (int mf = 0; mf < 4; ++mf)
#pragma unroll
      for (int r = 0; r < 4; ++r) {
        float s1 = 0.f, s2 = 0.f;
#pragma unroll
        for (int nf = 0; nf < NF1; ++nf) {
          float x = acc1[mf][nf][r];
          s1 += x; s2 += x * x;
        }
#pragma unroll
        for (int mk = 1; mk <= 8; mk <<= 1) {
          s1 += __shfl_xor(s1, mk, 64);
          s2 += __shfl_xor(s2, mk, 64);
        }
        if (l15 == 0) {
          int row = mf * 16 + g * 4 + r;
          red[row][wn][0] = s1;
          red[row][wn][1] = s2;
        }
      }
    __syncthreads();   // all waves done reading A1 panel
    if (tid < 64) {
      float s1 = 0.f, s2 = 0.f;
#pragma unroll
      for (int j = 0; j < 8; ++j) { s1 += red[tid][j][0]; s2 += red[tid][j][1]; }
      float mean = s1 / (float)N1;
      float var = s2 / (float)N1 - mean * mean;
      rowstat[tid][0] = mean;
      rowstat[tid][1] = rsqrtf(var + 1e-5f);
    }
    __syncthreads();
    // normalize + write h1 into panel (stride N1, same XOR swizzle)
#pragma unroll
    for (int mf = 0; mf < 4; ++mf)
#pragma unroll
      for (int r = 0; r < 4; ++r) {
        int row = mf * 16 + g * 4 + r;
        float mean = rowstat[row][0], rstd = rowstat[row][1];
#pragma unroll
        for (int nf = 0; nf < NF1; ++nf) {
          int col = wn * WC1 + nf * 16 + l15;
          float y = (acc1[mf][nf][r] - mean) * rstd * gam[nf] + bet[nf];
          int pos = (col & ~63) + ((((col >> 3) & 7) ^ (row & 7)) << 3) + (col & 7);
          smP[row * N1 + pos] = f2b(y);
        }
      }
  }

  // ---- GEMM2: acc2 = h1 @ W2 (ping-pong B queues) ----
  const unsigned short* W2e = W2 + (size_t)e * N2 * N1;
  const unsigned short* bp2[NF2];
#pragma unroll
  for (int nf = 0; nf < NF2; ++nf)
    bp2[nf] = W2e + (size_t)(wn * WC2 + nf * 16 + l15) * N1 + g * 8;

  f32x4 acc2[4][NF2] = {};
  bf16x8 pA[NF2], pB[NF2];
#pragma unroll
  for (int nf = 0; nf < NF2; ++nf) pA[nf] = *(const bf16x8*)(bp2[nf]);
  if (NS2 > 1) {
#pragma unroll
    for (int nf = 0; nf < NF2; ++nf) pB[nf] = *(const bf16x8*)(bp2[nf] + 32);
  }

  __syncthreads();   // h1 panel complete

#pragma unroll
  for (int ks = 0; ks < NS2; ++ks) {
    const int kt = ks >> 1, kk = ks & 1;
    bf16x8 a4[4];
#pragma unroll
    for (int mf = 0; mf < 4; ++mf) {
      int row = mf * 16 + l15;
      int chunk = (kk * 4 + g) ^ (row & 7);
      a4[mf] = *(const bf16x8*)(&smP[row * N1 + kt * 64 + chunk * 8]);
    }
    if ((ks & 1) == 0) {
#pragma unroll
      for (int mf = 0; mf < 4; ++mf)
#pragma unroll
        for (int nf = 0; nf < NF2; ++nf)
          acc2[mf][nf] = __builtin_amdgcn_mfma_f32_16x16x32_bf16(a4[mf], pA[nf], acc2[mf][nf], 0, 0, 0);
      if (ks + 2 < NS2) {
#pragma unroll
        for (int nf = 0; nf < NF2; ++nf) pA[nf] = *(const bf16x8*)(bp2[nf] + (ks + 2) * 32);
      }
    } else {
#pragma unroll
      for (int mf = 0; mf < 4; ++mf)
#pragma unroll
        for (int nf = 0; nf < NF2; ++nf)
          acc2[mf][nf] = __builtin_amdgcn_mfma_f32_16x16x32_bf16(a4[mf], pB[nf], acc2[mf][nf], 0, 0, 0);
      if (ks + 2 < NS2) {
#pragma unroll
        for (int nf = 0; nf < NF2; ++nf) pB[nf] = *(const bf16x8*)(bp2[nf] + (ks + 2) * 32);
      }
    }
  }

  // ---- bias + ELU + LN over N2 ----
  {
    float bia[NF2], gam[NF2], bet[NF2];
#pragma unroll
    for (int nf = 0; nf < NF2; ++nf) {
      int n = wn * WC2 + nf * 16 + l15;
      bia[nf] = b2v[e * N2 + n]; gam[nf] = g2v[e * N2 + n]; bet[nf] = h2v[e * N2 + n];
    }
#pragma unroll
    for (int mf = 0; mf < 4; ++mf)
#pragma unroll
      for (int nf = 0; nf < NF2; ++nf)
#pragma unroll
        for (int r = 0; r < 4; ++r)
          acc2[mf][nf][r] = fast_elu(acc2[mf][nf][r] + bia[nf]);
#pragma unroll
    for (int mf = 0; mf < 4; ++mf)
#pragma unroll
      for (int r = 0; r < 4; ++r) {
        float s1 = 0.f, s2 = 0.f;
#pragma unroll
        for (int nf = 0; nf < NF2; ++nf) {
          float x = acc2[mf][nf][r];
          s1 += x; s2 += x * x;
        }
#pragma unroll
        for (int mk = 1; mk <= 8; mk <<= 1) {
          s1 += __shfl_xor(s1, mk, 64);
          s2 += __shfl_xor(s2, mk, 64);
        }
        if (l15 == 0) {
          int row = mf * 16 + g * 4 + r;
          red[row][wn][0] = s1;
          red[row][wn][1] = s2;
        }
      }
    __syncthreads();   // all waves done reading h1 panel
    if (tid < 64) {
      float s1 = 0.f, s2 = 0.f;
#pragma unroll
      for (int j = 0; j < 8; ++j) { s1 += red[tid][j][0]; s2 += red[tid][j][1]; }
      float mean = s1 / (float)N2;
      float var = s2 / (float)N2 - mean * mean;
      rowstat[tid][0] = mean;
      rowstat[tid][1] = rsqrtf(var + 1e-5f);
    }
    __syncthreads();
#pragma unroll
    for (int mf = 0; mf < 4; ++mf)
#pragma unroll
      for (int r = 0; r < 4; ++r) {
        int row = mf * 16 + g * 4 + r;
        float mean = rowstat[row][0], rstd = rowstat[row][1];
#pragma unroll
        for (int nf = 0; nf < NF2; ++nf)
          acc2[mf][nf][r] = (acc2[mf][nf][r] - mean) * rstd * gam[nf] + bet[nf];
      }
  }

  if constexpr (!FCHAIN) {
    // ---- vectorized store via LDS staging, 128-col chunks ----
    unsigned short* sm16 = &smP[0];       // [64][128]
    int wq = (wn * WC2) >> 7;
    for (int q = 0; q < NCH; ++q) {
      __syncthreads();
      if (NCH == 1 || wq == q) {
#pragma unroll
        for (int mf = 0; mf < 4; ++mf)
#pragma unroll
          for (int r = 0; r < 4; ++r) {
            int row = mf * 16 + g * 4 + r;
            int s = row & 7;
#pragma unroll
            for (int nf = 0; nf < NF2; ++nf) {
              int lc = (wn * WC2 + nf * 16 + l15) - q * 128;   // 0..127
              if (NCH == 1 || (lc >= 0 && lc < 128)) {
                int pos = (((lc >> 3) ^ s) << 3) | (lc & 7);
                sm16[row * 128 + pos] = f2b(acc2[mf][nf][r]);
              }
            }
          }
      }
      __syncthreads();
#pragma unroll
      for (int i = 0; i < 2; ++i) {
        int t = tid + i * 512;
        int row = t >> 4, cc = t & 15;
        int oc = cc ^ (row & 7);
        uint4 v = *(const uint4*)(&sm16[row * 128 + cc * 8]);
        *(uint4*)(&Out[((size_t)e * CAP + rb + row) * Os + Ocol + q * 128 + oc * 8]) = v;
      }
    }
  } else {
    // ---- f-chain: h2 to LDS (padded) + fw3 staged to LDS, 256->12 head ----
    __syncthreads();   // acc2 final everywhere; panel free
    constexpr int H2S = 264;  // row stride (pad 8 to break bank alignment)
    float* wsh = (float*)(&smP[64 * H2S]);   // 12 KB, disjoint from h2 rows
#pragma unroll
    for (int mf = 0; mf < 4; ++mf)
#pragma unroll
      for (int r = 0; r < 4; ++r) {
        int row = mf * 16 + g * 4 + r;
#pragma unroll
        for (int nf = 0; nf < NF2; ++nf) {
          int col = wn * WC2 + nf * 16 + l15;
          smP[row * H2S + col] = f2b(acc2[mf][nf][r]);
        }
      }
    for (int i = tid; i < 256 * 12; i += 512) wsh[i] = fw3[(size_t)e * 256 * 12 + i];
    __syncthreads();
#pragma unroll
    for (int it = 0; it < 2; ++it) {
      int idx = tid + it * 512;
      if (idx < 768) {
        int row = idx / 12, j = idx - row * 12;
        int slot2 = rb + row;
        if (slot2 < count) {
          float a = fb3[e * 12 + j];
          for (int c = 0; c < 256; ++c)
            a += b2f(smP[row * H2S + c]) * wsh[c * 12 + j];
          int arow = perm[e * CAP + slot2];
          allout[((size_t)arow * 8 + e) * 12 + j] = a;
        }
      }
    }
  }
}

// ------- mix: weighted sum of the two selected expert outputs -------
__global__ void k_mix(const float* __restrict__ selbuf, const float* __restrict__ allout,
                      float* __restrict__ out) {
  int b = blockIdx.x * 256 + threadIdx.x;
  int i0 = (int)selbuf[(size_t)b * 4 + 0];
  int i1 = (int)selbuf[(size_t)b * 4 + 1];
  float w0 = selbuf[(size_t)b * 4 + 2];
  float w1 = selbuf[(size_t)b * 4 + 3];
  const float* a0 = allout + ((size_t)b * 8 + i0) * 12;
  const float* a1 = allout + ((size_t)b * 8 + i1) * 12;
#pragma unroll
  for (int j = 0; j < 12; ++j)
    out[(size_t)b * 12 + j] = w0 * a0[j] + w1 * a1[j];
}

// ---------------- host ----------------

extern "C" void kernel_launch(void* const* d_in, const int* in_sizes, int n_in,
                              void* d_out, int out_size, void* d_ws, size_t ws_size,
                              hipStream_t stream) {
  const float* state = (const float*)d_in[0];
  const float* vlm   = (const float*)d_in[1];
  const float* sw1 = (const float*)d_in[2];  const float* sb1 = (const float*)d_in[3];
  const float* sg1 = (const float*)d_in[4];  const float* sh1 = (const float*)d_in[5];
  const float* sw2 = (const float*)d_in[6];  const float* sb2 = (const float*)d_in[7];
  const float* sg2 = (const float*)d_in[8];  const float* sh2 = (const float*)d_in[9];
  const float* vw1 = (const float*)d_in[10]; const float* vb1 = (const float*)d_in[11];
  const float* vg1 = (const float*)d_in[12]; const float* vh1 = (const float*)d_in[13];
  const float* vw2 = (const float*)d_in[14]; const float* vb2 = (const float*)d_in[15];
  const float* vg2 = (const float*)d_in[16]; const float* vh2 = (const float*)d_in[17];
  const float* fw1 = (const float*)d_in[18]; const float* fb1 = (const float*)d_in[19];
  const float* fg1 = (const float*)d_in[20]; const float* fh1 = (const float*)d_in[21];
  const float* fw2 = (const float*)d_in[22]; const float* fb2 = (const float*)d_in[23];
  const float* fg2 = (const float*)d_in[24]; const float* fh2 = (const float*)d_in[25];
  const float* fw3 = (const float*)d_in[26]; const float* fb3 = (const float*)d_in[27];
  const float* gw1 = (const float*)d_in[28]; const float* gb1 = (const float*)d_in[29];
  const float* gw2 = (const float*)d_in[30]; const float* gb2 = (const float*)d_in[31];
  const float* gw3 = (const float*)d_in[32]; const float* gb3 = (const float*)d_in[33];

  // ---- workspace (~182 MB) ----
  char* ws = (char*)d_ws;
  size_t off = 0;
  auto alloc = [&](size_t bytes) -> char* {
    char* p = ws + off;
    off = (off + bytes + 255) & ~(size_t)255;
    return p;
  };
  unsigned short* st_bf = (unsigned short*)alloc((size_t)BROWS * 128 * 2);      // 8.4 MB
  unsigned short* vl_bf = (unsigned short*)alloc((size_t)BROWS * 512 * 2);      // 33.6 MB
  unsigned short* bufF  = (unsigned short*)alloc((size_t)NEXP * CAP * 384 * 2); // 62.9 MB
  float* allout = (float*)alloc((size_t)BROWS * 8 * 12 * 4);                    // 12.6 MB
  float* gh1    = (float*)alloc((size_t)BROWS * 256 * 4);                       // 33.6 MB
  float* gh2    = (float*)alloc((size_t)BROWS * 128 * 4);                       // 16.8 MB
  float* selbuf = (float*)alloc((size_t)BROWS * 4 * 4);
  int*   perm   = (int*)alloc((size_t)NEXP * CAP * 4);
  int*   bcnt   = (int*)alloc(512 * 8 * 4);
  int*   bbase  = (int*)alloc(512 * 8 * 4);
  char*  cntaux = alloc(256);  // cnt: 8 ints at +0, aux: 8 floats at +64
  int*   cnt = (int*)cntaux;
  float* aux = (float*)(cntaux + 64);
  unsigned short* wt_s1 = (unsigned short*)alloc((size_t)8 * 256 * 128 * 2);
  unsigned short* wt_s2 = (unsigned short*)alloc((size_t)8 * 128 * 256 * 2);
  unsigned short* wt_v1 = (unsigned short*)alloc((size_t)8 * 512 * 512 * 2);
  unsigned short* wt_v2 = (unsigned short*)alloc((size_t)8 * 256 * 512 * 2);
  unsigned short* wt_f1 = (unsigned short*)alloc((size_t)8 * 512 * 384 * 2);
  unsigned short* wt_f2 = (unsigned short*)alloc((size_t)8 * 256 * 512 * 2);
  (void)ws_size; (void)in_sizes; (void)n_in; (void)out_size;

  float* outf = (float*)d_out;

  // prep
  k_convert_pad<<<(BROWS * 128 + 255) / 256, 256, 0, stream>>>(state, st_bf, BROWS, 96, 128);
  k_convert_pad<<<(BROWS * 512 + 255) / 256, 256, 0, stream>>>(vlm, vl_bf, BROWS, 512, 512);
  k_wtrans<<<dim3(4, 8, 8),   dim3(32, 8), 0, stream>>>(sw1, wt_s1, 96, 256, 128);
  k_wtrans<<<dim3(8, 4, 8),   dim3(32, 8), 0, stream>>>(sw2, wt_s2, 256, 128, 256);
  k_wtrans<<<dim3(16, 16, 8), dim3(32, 8), 0, stream>>>(vw1, wt_v1, 512, 512, 512);
  k_wtrans<<<dim3(16, 8, 8),  dim3(32, 8), 0, stream>>>(vw2, wt_v2, 512, 256, 512);
  k_wtrans<<<dim3(12, 16, 8), dim3(32, 8), 0, stream>>>(fw1, wt_f1, 384, 512, 384);
  k_wtrans<<<dim3(16, 8, 8),  dim3(32, 8), 0, stream>>>(fw2, wt_f2, 512, 256, 512);
  k_zero<<<1, 64, 0, stream>>>((int*)cntaux, 64);

  // gate (fp32 for exact top-k)
  k_gemm32<true><<<dim3(256, 2), 256, 0, stream>>>(state, 96, vlm, 512, 96,
                                                   gw1, gb1, 608, 256, gh1);
  k_gemm32<false><<<dim3(256, 1), 256, 0, stream>>>(gh1, 256, nullptr, 0, 0,
                                                    gw2, gb2, 256, 128, gh2);
  k_gatetop<<<BROWS / 256, 256, 0, stream>>>(gh2, gw3, gb3, outf, aux, bcnt, selbuf);
  k_scan<<<1, 64, 0, stream>>>(bcnt, bbase, cnt);
  k_fill<<<512, 64, 0, stream>>>(selbuf, bbase, perm);
  k_auxfinal<<<1, 64, 0, stream>>>(cnt, aux, outf);

  // fused expert chains; 1D grid, e = bid & 7 -> expert-per-XCD L2 pinning
  const int NBLK = CAPBLK * NEXP;
  // s-chain: st_bf -> 256 -> 128 -> bufF[:, 0:128]
  k_chain<128, 256, 128, true, false><<<NBLK, 512, 0, stream>>>(
      st_bf, 128, perm, cnt,
      wt_s1, sb1, sg1, sh1, wt_s2, sb2, sg2, sh2,
      bufF, 384, 0, nullptr, nullptr, nullptr);
  // v-chain: vl_bf -> 512 -> 256 -> bufF[:, 128:384]
  k_chain<512, 512, 256, true, false><<<NBLK, 512, 0, stream>>>(
      vl_bf, 512, perm, cnt,
      wt_v1, vb1, vg1, vh1, wt_v2, vb2, vg2, vh2,
      bufF, 384, 128, nullptr, nullptr, nullptr);
  // f-chain: bufF -> 512 -> 256 -> head 12 -> allout
  k_chain<384, 512, 256, false, true><<<NBLK, 512, 0, stream>>>(
      bufF, 384, perm, cnt,
      wt_f1, fb1, fg1, fh1, wt_f2, fb2, fg2, fh2,
      nullptr, 0, 0, fw3, fb3, allout);

  k_mix<<<BROWS / 256, 256, 0, stream>>>(selbuf, allout, outf);
}